// Round 10
// baseline (136.570 us; speedup 1.0000x reference)
//
#include <hip/hip_runtime.h>
#include <hip/hip_bf16.h>
#include <math.h>

#define MDIM 1024
#define QTOT 65536
#define KTOP 16
#define ODIM 256
#define FDIM 512
#define TTILES 4

typedef float f32x4 __attribute__((ext_vector_type(4)));
typedef short s16x8 __attribute__((ext_vector_type(8)));
typedef unsigned u32x4 __attribute__((ext_vector_type(4)));

#if __has_builtin(__builtin_amdgcn_exp2f)
#define EXP2(x) __builtin_amdgcn_exp2f(x)
#else
#define EXP2(x) exp2f(x)
#endif

// pinned single-instruction min/max
#define VMIN(a,b)    ({float r_; asm("v_min_f32 %0,%1,%2":"=v"(r_):"v"(a),"v"(b)); r_;})
#define VMAX(a,b)    ({float r_; asm("v_max_f32 %0,%1,%2":"=v"(r_):"v"(a),"v"(b)); r_;})

__device__ __forceinline__ int read_mask(const void* m, int i, bool is8) {
  return is8 ? (int)((const unsigned char*)m)[i] : ((const int*)m)[i];
}

__device__ __forceinline__ unsigned pack2(float lo, float hi) {
  __hip_bfloat162 h = __float22bfloat162_rn(make_float2(lo, hi));
  unsigned u;
  __builtin_memcpy(&u, &h, sizeof(u));
  return u;
}

// ---------------- kernel 1: top-16 neighbor distances ----------------
// grid: QTOT/32 blocks x 256 threads. Block = 32 queries of one batch,
// 8 lanes per query. Selection: sort8 network + bitonic merge into sorted-16.
__global__ __launch_bounds__(256, 6) void topk_kernel(
    const float* __restrict__ coords, const void* __restrict__ mask,
    float* __restrict__ dists)
{
  __shared__ float4 pts[MDIM + 8];   // +8 pad: last-group overreads are poisoned
  __shared__ int posof[MDIM];        // atom -> compacted position (-1 if masked)
  __shared__ int s_cnt;
  __shared__ int s_is8;
  const int tid = threadIdx.x;
  const int lane = tid & 63;
  const int wv = tid >> 6;
  const int bid = blockIdx.x;
  const int batch = bid >> 5;      // 32 blocks per batch
  const int qchunk = bid & 31;

  if (tid == 0) { s_cnt = 0; s_is8 = 0; }
  __syncthreads();
  { // mask dtype detection: int32 0/1 words vs packed int8 bools
    unsigned w = ((const unsigned*)mask)[tid & 255];
    if (w > 1u) atomicOr(&s_is8, 1);
  }
  __syncthreads();
  const bool is8 = (s_is8 != 0);

  const float* cb = coords + (size_t)batch * MDIM * 3;
  const int mbase = batch * MDIM;

  // compact valid atoms into LDS: (x,y,z,|p|^2)
  #pragma unroll
  for (int r = 0; r < 4; ++r) {
    int a = r * 256 + tid;
    int v = read_mask(mask, mbase + a, is8);
    float x = cb[a*3+0], y = cb[a*3+1], z = cb[a*3+2];
    float S = fmaf(z, z, fmaf(y, y, x * x));
    unsigned long long bal = __ballot(v != 0);
    int base = 0;
    if (lane == 0) base = atomicAdd(&s_cnt, __popcll(bal));
    base = __shfl(base, 0);
    int pos = base + __popcll(bal & ((1ull << lane) - 1ull));
    if (v) {
      float4 p; p.x = x; p.y = y; p.z = z; p.w = S;
      pts[pos] = p;
    }
    posof[a] = v ? pos : -1;
  }
  __syncthreads();
  const int cnt = s_cnt;

  // 8 lanes per query: lane = qi + 8*part
  const int qi = lane & 7;
  const int part = lane >> 3;
  const int qlocal = qchunk * 32 + wv * 8 + qi;
  const float qx = cb[qlocal*3+0], qy = cb[qlocal*3+1], qz = cb[qlocal*3+2];
  const float Q = fmaf(qz, qz, fmaf(qy, qy, qx * qx));
  const float m2x = -2.0f * qx, m2y = -2.0f * qy, m2z = -2.0f * qz;
  const int selfpos = posof[qlocal];
  const int lo = (cnt * part) >> 3;
  const int hi = (cnt * (part + 1)) >> 3;

  float t[16];
  #pragma unroll
  for (int i = 0; i < 16; ++i) t[i] = 3.0e38f;

  const int len = hi - lo;
  const int ng = (len + 7) >> 3;
  for (int g = 0; g < ng; ++g) {
    const int base = lo + g * 8;
    float s[8];
    #pragma unroll
    for (int i = 0; i < 8; ++i) {
      int idx = base + i;
      float4 p = pts[idx];
      // d' = |p|^2 - 2 q.p  (= d^2 - Q, order-preserving)
      float d = fmaf(p.z, m2z, fmaf(p.y, m2y, fmaf(p.x, m2x, p.w)));
      d = (idx == selfpos) ? 3.0e38f : d;   // exclude self
      s[i] = (idx < hi) ? d : 3.0e38f;      // ragged-tail poison
    }
    // Batcher sort-8 (19 CE)
    #define CES(i,j) { float mn_ = VMIN(s[i], s[j]); float mx_ = VMAX(s[i], s[j]); s[i] = mn_; s[j] = mx_; }
    CES(0,1) CES(2,3) CES(4,5) CES(6,7)
    CES(0,2) CES(1,3) CES(4,6) CES(5,7)
    CES(1,2) CES(5,6)
    CES(0,4) CES(1,5) CES(2,6) CES(3,7)
    CES(2,4) CES(3,5)
    CES(1,2) CES(3,4) CES(5,6)
    #undef CES
    // half-clean: t[8..15] vs reversed s  -> t becomes bitonic, holds 16 smallest
    #pragma unroll
    for (int i = 0; i < 8; ++i) t[8 + i] = VMIN(t[8 + i], s[7 - i]);
    // bitonic clean of 16
    #define CET(i,j) { float mn_ = VMIN(t[i], t[j]); float mx_ = VMAX(t[i], t[j]); t[i] = mn_; t[j] = mx_; }
    CET(0,8) CET(1,9) CET(2,10) CET(3,11) CET(4,12) CET(5,13) CET(6,14) CET(7,15)
    CET(0,4) CET(1,5) CET(2,6)  CET(3,7)  CET(8,12) CET(9,13) CET(10,14) CET(11,15)
    CET(0,2) CET(1,3) CET(4,6)  CET(5,7)  CET(8,10) CET(9,11) CET(12,14) CET(13,15)
    CET(0,1) CET(2,3) CET(4,5)  CET(6,7)  CET(8,9)  CET(10,11) CET(12,13) CET(14,15)
    #undef CET
  }

  // merge the 8 part-lists: bitonic merges with partners ^8, ^16, ^32
  #pragma unroll
  for (int stepi = 0; stepi < 3; ++stepi) {
    const int step = 8 << stepi;
    float o_[16], m[16];
    #pragma unroll
    for (int i = 0; i < 16; ++i) o_[i] = __shfl(t[i], lane ^ step);
    #pragma unroll
    for (int i = 0; i < 16; ++i) m[i] = VMIN(t[i], o_[15 - i]);
    #define CE(i,jj) { float a_ = VMIN(m[i], m[jj]); float b_ = VMAX(m[i], m[jj]); m[i] = a_; m[jj] = b_; }
    CE(0,8) CE(1,9) CE(2,10) CE(3,11) CE(4,12) CE(5,13) CE(6,14) CE(7,15)
    CE(0,4) CE(1,5) CE(2,6)  CE(3,7)  CE(8,12) CE(9,13) CE(10,14) CE(11,15)
    CE(0,2) CE(1,3) CE(4,6)  CE(5,7)  CE(8,10) CE(9,11) CE(12,14) CE(13,15)
    CE(0,1) CE(2,3) CE(4,5)  CE(6,7)  CE(8,9)  CE(10,11) CE(12,13) CE(14,15)
    #undef CE
    #pragma unroll
    for (int i = 0; i < 16; ++i) t[i] = m[i];
  }

  if (part == 0) {
    int mq = read_mask(mask, mbase + qlocal, is8);
    float res[16];
    #pragma unroll
    for (int i = 0; i < 16; ++i) {
      float v = t[i];
      float d = (v > 1.0e37f) ? 24.0f : sqrtf(fmaxf(v + Q, 1e-12f)); // pad -> MAX_DIST
      res[i] = mq ? d : -1.0f;   // -1 sentinel => output row forced to zero
    }
    float4* dst = (float4*)(dists + (size_t)(mbase + qlocal) * KTOP);
    float4 o0, o1, o2, o3;
    o0.x=res[0];  o0.y=res[1];  o0.z=res[2];  o0.w=res[3];
    o1.x=res[4];  o1.y=res[5];  o1.z=res[6];  o1.w=res[7];
    o2.x=res[8];  o2.y=res[9];  o2.z=res[10]; o2.w=res[11];
    o3.x=res[12]; o3.y=res[13]; o3.z=res[14]; o3.w=res[15];
    dst[0]=o0; dst[1]=o1; dst[2]=o2; dst[3]=o3;
  }
}

// ---------------- kernel 2: fused RBF + projection (bf16 MFMA) ----------------
// grid: QTOT/128 = 512 blocks x 512 threads (8 waves) = exactly 2 blocks/CU.
// Block covers ALL 256 cols (A gen'd once). Double-buffered A (66.5 KB):
// gen(t+1) overlaps MFMA(t). C parks into the just-read A buffer (exact fit),
// then written tid-linear: one wave = one full 1KB output row (clean stream).
constexpr double SPd = 24.0 / 31.0;
constexpr double SP2d = SPd * SPd;
constexpr float ALPHA = (float)(-(SP2d / (SP2d + 1e-8)) * 1.4426950408889634);
constexpr float INV_SP = (float)(1.0 / SPd);

__device__ __forceinline__ void gen_cell(u32x4* Ah, int rowh, int s, float d0) {
  float d = (d0 < 0.f) ? 1.0e9f : d0;   // sentinel -> rbf == 0
  float u = d * INV_SP;
  float C1 = (-2.0f * ALPHA) * u;
  float C0 = ALPHA * u * u;
  #pragma unroll
  for (int c8 = 0; c8 < 4; ++c8) {
    u32x4 ch;
    #pragma unroll
    for (int q = 0; q < 4; ++q) {
      const int j0 = c8 * 8 + q * 2;
      float e0 = EXP2(fmaf(C1, (float)j0,       C0) + ALPHA * (float)(j0 * j0));
      float e1 = EXP2(fmaf(C1, (float)(j0 + 1), C0) + ALPHA * (float)((j0 + 1) * (j0 + 1)));
      ch[q] = pack2(e0, e1);
    }
    Ah[s * 65 + c8 * 16 + rowh] = ch;
  }
}

__global__ __launch_bounds__(512, 4) void rbf_gemm_kernel(
    const float* __restrict__ dists, const float* __restrict__ W,
    float* __restrict__ out)
{
  __shared__ u32x4 A_sh[2][2][1040];   // [buf][row-half][s*65 + fragslot]; 66560 B

  const int tid = threadIdx.x;
  const int lane = tid & 63;
  const int wv = tid >> 6;                 // 0..7
  const int c0 = wv * 32 + (lane & 15);    // out col (set 0); set 1 = +16
  const int ksub = (lane >> 4) * 8;

  // preload W fragments for this wave's 2 col-sets (MFMA B operand)
  s16x8 bf0[16], bf1[16];
  const float* wr0 = W + (size_t)c0 * FDIM;
  const float* wr1 = wr0 + (size_t)16 * FDIM;
  #pragma unroll
  for (int s = 0; s < 16; ++s) {
    const float4* p0 = (const float4*)(wr0 + s * 32 + ksub);
    const float4* p1 = (const float4*)(wr1 + s * 32 + ksub);
    float4 a = p0[0], b = p0[1], c = p1[0], d = p1[1];
    u32x4 u0, u1;
    u0[0] = pack2(a.x, a.y); u0[1] = pack2(a.z, a.w);
    u0[2] = pack2(b.x, b.y); u0[3] = pack2(b.z, b.w);
    u1[0] = pack2(c.x, c.y); u1[1] = pack2(c.z, c.w);
    u1[2] = pack2(d.x, d.y); u1[3] = pack2(d.z, d.w);
    __builtin_memcpy(&bf0[s], &u0, sizeof(u0));
    __builtin_memcpy(&bf1[s], &u1, sizeof(u1));
  }

  // gen cell: one (row, slot) per thread; row 0..31, slot 0..15
  const int half = tid >> 8;             // row-half 0/1
  const int rowh = (tid >> 4) & 15;
  const int sgen = tid & 15;
  const int qbase0 = blockIdx.x * (32 * TTILES);
  const size_t dbase = (size_t)qbase0 * KTOP;

  float dcur = dists[dbase + tid];          // tile 0 (coalesced: cell == tid)
  float dnxt = dists[dbase + 512 + tid];    // tile 1
  gen_cell(A_sh[0][half], rowh, sgen, dcur);

  for (int t = 0; t < TTILES; ++t) {
    const int cur = t & 1, nx = cur ^ 1;
    __syncthreads();   // A[cur] gen complete; A[nx]'s store-reads (t-1) complete

    if (t + 1 < TTILES) gen_cell(A_sh[nx][half], rowh, sgen, dnxt);
    if (t + 2 < TTILES) dnxt = dists[dbase + (size_t)(t + 2) * 512 + tid];

    f32x4 acc00 = {0.f,0.f,0.f,0.f}, acc01 = {0.f,0.f,0.f,0.f};
    f32x4 acc10 = {0.f,0.f,0.f,0.f}, acc11 = {0.f,0.f,0.f,0.f};
    #pragma unroll
    for (int s = 0; s < 16; ++s) {
      s16x8 a0, a1;
      u32x4 ra0 = A_sh[cur][0][s * 65 + lane];
      u32x4 ra1 = A_sh[cur][1][s * 65 + lane];
      __builtin_memcpy(&a0, &ra0, sizeof(ra0));
      __builtin_memcpy(&a1, &ra1, sizeof(ra1));
      // rbf as A (m = out row), W as B (n = out col)
      acc00 = __builtin_amdgcn_mfma_f32_16x16x32_bf16(a0, bf0[s], acc00, 0, 0, 0);
      acc01 = __builtin_amdgcn_mfma_f32_16x16x32_bf16(a0, bf1[s], acc01, 0, 0, 0);
      acc10 = __builtin_amdgcn_mfma_f32_16x16x32_bf16(a1, bf0[s], acc10, 0, 0, 0);
      acc11 = __builtin_amdgcn_mfma_f32_16x16x32_bf16(a1, bf1[s], acc11, 0, 0, 0);
    }
    __syncthreads();   // all waves done reading A[cur] -> safe to park C there

    // park C into A[cur] viewed as float C[32][260] (33280 B, exact fit)
    float* C = (float*)&A_sh[cur][0][0];
    const int rb = (lane >> 4) * 4;
    #pragma unroll
    for (int r = 0; r < 4; ++r) {
      C[(rb + r) * 260 + c0]           = acc00[r];
      C[(rb + r) * 260 + c0 + 16]      = acc01[r];
      C[(16 + rb + r) * 260 + c0]      = acc10[r];
      C[(16 + rb + r) * 260 + c0 + 16] = acc11[r];
    }
    __syncthreads();   // C visible

    // tid-linear write-out: wave w writes row (p*8 + w), 64 lanes x 16B = 1KB
    const int qbase = qbase0 + t * 32;
    #pragma unroll
    for (int p = 0; p < 4; ++p) {
      const int row = p * 8 + wv;
      f32x4 v = *(const f32x4*)&C[row * 260 + lane * 4];
      *(f32x4*)(out + (size_t)(qbase + row) * ODIM + lane * 4) = v;
    }
    // next iteration's first barrier fences these C-reads before gen overwrites
  }
}

extern "C" void kernel_launch(void* const* d_in, const int* in_sizes, int n_in,
                              void* d_out, int out_size, void* d_ws, size_t ws_size,
                              hipStream_t stream) {
  const float* coords = (const float*)d_in[0];
  const void* mask = d_in[1];
  const float* W = (const float*)d_in[2];
  float* out = (float*)d_out;
  float* dists = (float*)d_ws;   // QTOT * 16 fp32 = 4 MB scratch

  hipLaunchKernelGGL(topk_kernel, dim3(QTOT / 32), dim3(256), 0, stream,
                     coords, mask, dists);
  hipLaunchKernelGGL(rbf_gemm_kernel, dim3(QTOT / (32 * TTILES)), dim3(512), 0, stream,
                     dists, W, out);
}

// Round 11
// 82.953 us; speedup vs baseline: 1.6464x; 1.6464x over previous
//
#include <hip/hip_runtime.h>
#include <hip/hip_bf16.h>
#include <math.h>

#define MDIM 1024
#define QTOT 65536
#define KTOP 16
#define ODIM 256
#define FDIM 512
#define TTILES 8

typedef float f32x4 __attribute__((ext_vector_type(4)));
typedef short s16x8 __attribute__((ext_vector_type(8)));
typedef unsigned u32x4 __attribute__((ext_vector_type(4)));

#if __has_builtin(__builtin_amdgcn_exp2f)
#define EXP2(x) __builtin_amdgcn_exp2f(x)
#else
#define EXP2(x) exp2f(x)
#endif

// pinned single-instruction min/max
#define VMIN(a,b)    ({float r_; asm("v_min_f32 %0,%1,%2":"=v"(r_):"v"(a),"v"(b)); r_;})
#define VMAX(a,b)    ({float r_; asm("v_max_f32 %0,%1,%2":"=v"(r_):"v"(a),"v"(b)); r_;})

__device__ __forceinline__ int read_mask(const void* m, int i, bool is8) {
  return is8 ? (int)((const unsigned char*)m)[i] : ((const int*)m)[i];
}

__device__ __forceinline__ unsigned pack2(float lo, float hi) {
  __hip_bfloat162 h = __float22bfloat162_rn(make_float2(lo, hi));
  unsigned u;
  __builtin_memcpy(&u, &h, sizeof(u));
  return u;
}

// ---------------- kernel 1: top-16 neighbor distances ----------------
// grid: QTOT/32 blocks x 256 threads. Block = 32 queries of one batch,
// 8 lanes per query. Selection: sort8 network + bitonic merge into sorted-16.
__global__ __launch_bounds__(256, 6) void topk_kernel(
    const float* __restrict__ coords, const void* __restrict__ mask,
    float* __restrict__ dists)
{
  __shared__ float4 pts[MDIM + 8];   // +8 pad: last-group overreads are poisoned
  __shared__ int posof[MDIM];        // atom -> compacted position (-1 if masked)
  __shared__ int s_cnt;
  __shared__ int s_is8;
  const int tid = threadIdx.x;
  const int lane = tid & 63;
  const int wv = tid >> 6;
  const int bid = blockIdx.x;
  const int batch = bid >> 5;      // 32 blocks per batch
  const int qchunk = bid & 31;

  if (tid == 0) { s_cnt = 0; s_is8 = 0; }
  __syncthreads();
  { // mask dtype detection: int32 0/1 words vs packed int8 bools
    unsigned w = ((const unsigned*)mask)[tid & 255];
    if (w > 1u) atomicOr(&s_is8, 1);
  }
  __syncthreads();
  const bool is8 = (s_is8 != 0);

  const float* cb = coords + (size_t)batch * MDIM * 3;
  const int mbase = batch * MDIM;

  // compact valid atoms into LDS: (x,y,z,|p|^2)
  #pragma unroll
  for (int r = 0; r < 4; ++r) {
    int a = r * 256 + tid;
    int v = read_mask(mask, mbase + a, is8);
    float x = cb[a*3+0], y = cb[a*3+1], z = cb[a*3+2];
    float S = fmaf(z, z, fmaf(y, y, x * x));
    unsigned long long bal = __ballot(v != 0);
    int base = 0;
    if (lane == 0) base = atomicAdd(&s_cnt, __popcll(bal));
    base = __shfl(base, 0);
    int pos = base + __popcll(bal & ((1ull << lane) - 1ull));
    if (v) {
      float4 p; p.x = x; p.y = y; p.z = z; p.w = S;
      pts[pos] = p;
    }
    posof[a] = v ? pos : -1;
  }
  __syncthreads();
  const int cnt = s_cnt;

  // 8 lanes per query: lane = qi + 8*part
  const int qi = lane & 7;
  const int part = lane >> 3;
  const int qlocal = qchunk * 32 + wv * 8 + qi;
  const float qx = cb[qlocal*3+0], qy = cb[qlocal*3+1], qz = cb[qlocal*3+2];
  const float Q = fmaf(qz, qz, fmaf(qy, qy, qx * qx));
  const float m2x = -2.0f * qx, m2y = -2.0f * qy, m2z = -2.0f * qz;
  const int selfpos = posof[qlocal];
  const int lo = (cnt * part) >> 3;
  const int hi = (cnt * (part + 1)) >> 3;

  float t[16];
  #pragma unroll
  for (int i = 0; i < 16; ++i) t[i] = 3.0e38f;

  const int len = hi - lo;
  const int ng = (len + 7) >> 3;
  for (int g = 0; g < ng; ++g) {
    const int base = lo + g * 8;
    float s[8];
    #pragma unroll
    for (int i = 0; i < 8; ++i) {
      int idx = base + i;
      float4 p = pts[idx];
      // d' = |p|^2 - 2 q.p  (= d^2 - Q, order-preserving)
      float d = fmaf(p.z, m2z, fmaf(p.y, m2y, fmaf(p.x, m2x, p.w)));
      d = (idx == selfpos) ? 3.0e38f : d;   // exclude self
      s[i] = (idx < hi) ? d : 3.0e38f;      // ragged-tail poison
    }
    // Batcher sort-8 (19 CE)
    #define CES(i,j) { float mn_ = VMIN(s[i], s[j]); float mx_ = VMAX(s[i], s[j]); s[i] = mn_; s[j] = mx_; }
    CES(0,1) CES(2,3) CES(4,5) CES(6,7)
    CES(0,2) CES(1,3) CES(4,6) CES(5,7)
    CES(1,2) CES(5,6)
    CES(0,4) CES(1,5) CES(2,6) CES(3,7)
    CES(2,4) CES(3,5)
    CES(1,2) CES(3,4) CES(5,6)
    #undef CES
    // half-clean: t[8..15] vs reversed s  -> t becomes bitonic, holds 16 smallest
    #pragma unroll
    for (int i = 0; i < 8; ++i) t[8 + i] = VMIN(t[8 + i], s[7 - i]);
    // bitonic clean of 16
    #define CET(i,j) { float mn_ = VMIN(t[i], t[j]); float mx_ = VMAX(t[i], t[j]); t[i] = mn_; t[j] = mx_; }
    CET(0,8) CET(1,9) CET(2,10) CET(3,11) CET(4,12) CET(5,13) CET(6,14) CET(7,15)
    CET(0,4) CET(1,5) CET(2,6)  CET(3,7)  CET(8,12) CET(9,13) CET(10,14) CET(11,15)
    CET(0,2) CET(1,3) CET(4,6)  CET(5,7)  CET(8,10) CET(9,11) CET(12,14) CET(13,15)
    CET(0,1) CET(2,3) CET(4,5)  CET(6,7)  CET(8,9)  CET(10,11) CET(12,13) CET(14,15)
    #undef CET
  }

  // merge the 8 part-lists: bitonic merges with partners ^8, ^16, ^32
  #pragma unroll
  for (int stepi = 0; stepi < 3; ++stepi) {
    const int step = 8 << stepi;
    float o_[16], m[16];
    #pragma unroll
    for (int i = 0; i < 16; ++i) o_[i] = __shfl(t[i], lane ^ step);
    #pragma unroll
    for (int i = 0; i < 16; ++i) m[i] = VMIN(t[i], o_[15 - i]);
    #define CE(i,jj) { float a_ = VMIN(m[i], m[jj]); float b_ = VMAX(m[i], m[jj]); m[i] = a_; m[jj] = b_; }
    CE(0,8) CE(1,9) CE(2,10) CE(3,11) CE(4,12) CE(5,13) CE(6,14) CE(7,15)
    CE(0,4) CE(1,5) CE(2,6)  CE(3,7)  CE(8,12) CE(9,13) CE(10,14) CE(11,15)
    CE(0,2) CE(1,3) CE(4,6)  CE(5,7)  CE(8,10) CE(9,11) CE(12,14) CE(13,15)
    CE(0,1) CE(2,3) CE(4,5)  CE(6,7)  CE(8,9)  CE(10,11) CE(12,13) CE(14,15)
    #undef CE
    #pragma unroll
    for (int i = 0; i < 16; ++i) t[i] = m[i];
  }

  if (part == 0) {
    int mq = read_mask(mask, mbase + qlocal, is8);
    float res[16];
    #pragma unroll
    for (int i = 0; i < 16; ++i) {
      float v = t[i];
      float d = (v > 1.0e37f) ? 24.0f : sqrtf(fmaxf(v + Q, 1e-12f)); // pad -> MAX_DIST
      res[i] = mq ? d : -1.0f;   // -1 sentinel => output row forced to zero
    }
    float4* dst = (float4*)(dists + (size_t)(mbase + qlocal) * KTOP);
    float4 o0, o1, o2, o3;
    o0.x=res[0];  o0.y=res[1];  o0.z=res[2];  o0.w=res[3];
    o1.x=res[4];  o1.y=res[5];  o1.z=res[6];  o1.w=res[7];
    o2.x=res[8];  o2.y=res[9];  o2.z=res[10]; o2.w=res[11];
    o3.x=res[12]; o3.y=res[13]; o3.z=res[14]; o3.w=res[15];
    dst[0]=o0; dst[1]=o1; dst[2]=o2; dst[3]=o3;
  }
}

// ---------------- kernel 2: fused RBF + projection (bf16 MFMA) ----------------
// grid: (4 n-blocks, 256 m-blocks) x 256 threads (4 waves).
// Wave owns 16 cols -> ONE bfrag[16] = 64 VGPRs (fits: the 2-col-set variants
// needed 128 frag VGPRs, spilled to scratch, and scratch reload traffic was the
// 2-3x WRITE + output-sized FETCH seen in R5-R10). Single A buffer (33 KB,
// 4 blocks/CU), 2 barriers/tile; stores use the R1-proven clean scalar pattern
// (16 adjacent lanes = 64B runs) and overlap the next tile's gen.
constexpr double SPd = 24.0 / 31.0;
constexpr double SP2d = SPd * SPd;
constexpr float ALPHA = (float)(-(SP2d / (SP2d + 1e-8)) * 1.4426950408889634);
constexpr float INV_SP = (float)(1.0 / SPd);

__device__ __forceinline__ void gen_tile(u32x4 (*Abuf)[1040], int row0, int s,
                                         float d0, float d1) {
  float dd0 = (d0 < 0.f) ? 1.0e9f : d0;   // sentinel -> rbf == 0
  float dd1 = (d1 < 0.f) ? 1.0e9f : d1;
  #pragma unroll
  for (int i = 0; i < 2; ++i) {
    float d = i ? dd1 : dd0;
    float u = d * INV_SP;
    float C1 = (-2.0f * ALPHA) * u;
    float C0 = ALPHA * u * u;
    #pragma unroll
    for (int c8 = 0; c8 < 4; ++c8) {
      u32x4 ch;
      #pragma unroll
      for (int q = 0; q < 4; ++q) {
        const int j0 = c8 * 8 + q * 2;
        float e0 = EXP2(fmaf(C1, (float)j0,       C0) + ALPHA * (float)(j0 * j0));
        float e1 = EXP2(fmaf(C1, (float)(j0 + 1), C0) + ALPHA * (float)((j0 + 1) * (j0 + 1)));
        ch[q] = pack2(e0, e1);
      }
      Abuf[i][s * 65 + c8 * 16 + row0] = ch;
    }
  }
}

__global__ __launch_bounds__(256, 4) void rbf_gemm_kernel(
    const float* __restrict__ dists, const float* __restrict__ W,
    float* __restrict__ out)
{
  __shared__ u32x4 A_sh[2][1040];   // [row-half][s*65 + fragslot]; 33280 B

  const int tid = threadIdx.x;
  const int lane = tid & 63;
  const int wv = tid >> 6;                              // 0..3
  const int c0 = blockIdx.x * 64 + wv * 16 + (lane & 15);  // this lane's out col
  const int ksub = (lane >> 4) * 8;

  // preload W fragments (MFMA B operand; n = out col): 16 x s16x8 = 64 VGPRs
  s16x8 bfrag[16];
  const float* wr = W + (size_t)c0 * FDIM;
  #pragma unroll
  for (int s = 0; s < 16; ++s) {
    const float4* p = (const float4*)(wr + s * 32 + ksub);
    float4 a = p[0], b = p[1];
    u32x4 u0;
    u0[0] = pack2(a.x, a.y); u0[1] = pack2(a.z, a.w);
    u0[2] = pack2(b.x, b.y); u0[3] = pack2(b.z, b.w);
    __builtin_memcpy(&bfrag[s], &u0, sizeof(u0));
  }

  const int row0 = tid >> 4;       // gen cell: rows row0 and row0+16, slot sgen
  const int sgen = tid & 15;
  const int qbase0 = blockIdx.y * (32 * TTILES);
  const size_t dbase = (size_t)qbase0 * KTOP;

  float c0v = dists[dbase + tid];          // tile 0 (cell == tid, coalesced)
  float c1v = dists[dbase + 256 + tid];

  for (int t = 0; t < TTILES; ++t) {
    gen_tile(A_sh, row0, sgen, c0v, c1v);
    if (t + 1 < TTILES) {
      c0v = dists[dbase + (size_t)(t + 1) * 512 + tid];
      c1v = dists[dbase + (size_t)(t + 1) * 512 + 256 + tid];
    }
    __syncthreads();   // A gen complete

    f32x4 acc0 = {0.f,0.f,0.f,0.f}, acc1 = {0.f,0.f,0.f,0.f};
    #pragma unroll
    for (int s = 0; s < 16; ++s) {
      s16x8 a0, a1;
      u32x4 ra0 = A_sh[0][s * 65 + lane];
      u32x4 ra1 = A_sh[1][s * 65 + lane];
      __builtin_memcpy(&a0, &ra0, sizeof(ra0));
      __builtin_memcpy(&a1, &ra1, sizeof(ra1));
      // rbf as A (m = out row), W as B (n = out col)
      acc0 = __builtin_amdgcn_mfma_f32_16x16x32_bf16(a0, bfrag[s], acc0, 0, 0, 0);
      acc1 = __builtin_amdgcn_mfma_f32_16x16x32_bf16(a1, bfrag[s], acc1, 0, 0, 0);
    }
    __syncthreads();   // all LDS reads done -> next gen may overwrite

    // stores (regs only) overlap next tile's gen
    const int qbase = qbase0 + t * 32;
    const int rb = (lane >> 4) * 4;
    #pragma unroll
    for (int r = 0; r < 4; ++r) {
      out[(size_t)(qbase + rb + r) * ODIM + c0]      = acc0[r];
      out[(size_t)(qbase + 16 + rb + r) * ODIM + c0] = acc1[r];
    }
  }
}

extern "C" void kernel_launch(void* const* d_in, const int* in_sizes, int n_in,
                              void* d_out, int out_size, void* d_ws, size_t ws_size,
                              hipStream_t stream) {
  const float* coords = (const float*)d_in[0];
  const void* mask = d_in[1];
  const float* W = (const float*)d_in[2];
  float* out = (float*)d_out;
  float* dists = (float*)d_ws;   // QTOT * 16 fp32 = 4 MB scratch

  hipLaunchKernelGGL(topk_kernel, dim3(QTOT / 32), dim3(256), 0, stream,
                     coords, mask, dists);
  hipLaunchKernelGGL(rbf_gemm_kernel, dim3(4, QTOT / (32 * TTILES)), dim3(256), 0, stream,
                     dists, W, out);
}

// Round 12
// 70.882 us; speedup vs baseline: 1.9267x; 1.1703x over previous
//
#include <hip/hip_runtime.h>
#include <hip/hip_bf16.h>
#include <math.h>

#define MDIM 1024
#define QTOT 65536
#define KTOP 16
#define ODIM 256
#define FDIM 512

typedef float f32x4 __attribute__((ext_vector_type(4)));
typedef short s16x8 __attribute__((ext_vector_type(8)));
typedef unsigned u32x4 __attribute__((ext_vector_type(4)));

#if __has_builtin(__builtin_amdgcn_exp2f)
#define EXP2(x) __builtin_amdgcn_exp2f(x)
#else
#define EXP2(x) exp2f(x)
#endif

// pinned single-instruction min/max
#define VMIN(a,b)    ({float r_; asm("v_min_f32 %0,%1,%2":"=v"(r_):"v"(a),"v"(b)); r_;})
#define VMAX(a,b)    ({float r_; asm("v_max_f32 %0,%1,%2":"=v"(r_):"v"(a),"v"(b)); r_;})

__device__ __forceinline__ int read_mask(const void* m, int i, bool is8) {
  return is8 ? (int)((const unsigned char*)m)[i] : ((const int*)m)[i];
}

__device__ __forceinline__ unsigned pack2(float lo, float hi) {
  __hip_bfloat162 h = __float22bfloat162_rn(make_float2(lo, hi));
  unsigned u;
  __builtin_memcpy(&u, &h, sizeof(u));
  return u;
}

// ---------------- kernel 0: W fp32 -> bf16 fragment-layout prepass ----------
// Wb[cg][s][lane] (u32x4): cg = e*4 + w encodes col-group (16 cols), s = k-slice,
// lane = h*16 + cl: 8 bf16 = W[col = (cg>>2)*64 + (cg&3)*16 + cl][s*32 + h*8 ..+8]
__global__ __launch_bounds__(256) void wconv_kernel(
    const float* __restrict__ W, u32x4* __restrict__ Wb)
{
  const int cg = blockIdx.x;           // 0..15
  const int tid = threadIdx.x;
  #pragma unroll
  for (int i = 0; i < 4; ++i) {
    int slot = tid + 256 * i;          // 0..1023
    int s = slot >> 6, l = slot & 63;
    int col = (cg >> 2) * 64 + (cg & 3) * 16 + (l & 15);
    int kk = s * 32 + (l >> 4) * 8;
    const float4* p = (const float4*)(W + (size_t)col * FDIM + kk);
    float4 a = p[0], b = p[1];
    u32x4 u0;
    u0[0] = pack2(a.x, a.y); u0[1] = pack2(a.z, a.w);
    u0[2] = pack2(b.x, b.y); u0[3] = pack2(b.z, b.w);
    Wb[(size_t)(cg * 16 + s) * 64 + l] = u0;
  }
}

// ---------------- kernel 1: top-16 neighbor distances ----------------
__global__ __launch_bounds__(256, 6) void topk_kernel(
    const float* __restrict__ coords, const void* __restrict__ mask,
    float* __restrict__ dists)
{
  __shared__ float4 pts[MDIM + 8];   // +8 pad: last-group overreads are poisoned
  __shared__ int posof[MDIM];
  __shared__ int s_cnt;
  __shared__ int s_is8;
  const int tid = threadIdx.x;
  const int lane = tid & 63;
  const int wv = tid >> 6;
  const int bid = blockIdx.x;
  const int batch = bid >> 5;      // 32 blocks per batch
  const int qchunk = bid & 31;

  if (tid == 0) { s_cnt = 0; s_is8 = 0; }
  __syncthreads();
  { // mask dtype detection: int32 0/1 words vs packed int8 bools
    unsigned w = ((const unsigned*)mask)[tid & 255];
    if (w > 1u) atomicOr(&s_is8, 1);
  }
  __syncthreads();
  const bool is8 = (s_is8 != 0);

  const float* cb = coords + (size_t)batch * MDIM * 3;
  const int mbase = batch * MDIM;

  #pragma unroll
  for (int r = 0; r < 4; ++r) {
    int a = r * 256 + tid;
    int v = read_mask(mask, mbase + a, is8);
    float x = cb[a*3+0], y = cb[a*3+1], z = cb[a*3+2];
    float S = fmaf(z, z, fmaf(y, y, x * x));
    unsigned long long bal = __ballot(v != 0);
    int base = 0;
    if (lane == 0) base = atomicAdd(&s_cnt, __popcll(bal));
    base = __shfl(base, 0);
    int pos = base + __popcll(bal & ((1ull << lane) - 1ull));
    if (v) {
      float4 p; p.x = x; p.y = y; p.z = z; p.w = S;
      pts[pos] = p;
    }
    posof[a] = v ? pos : -1;
  }
  __syncthreads();
  const int cnt = s_cnt;

  const int qi = lane & 7;
  const int part = lane >> 3;
  const int qlocal = qchunk * 32 + wv * 8 + qi;
  const float qx = cb[qlocal*3+0], qy = cb[qlocal*3+1], qz = cb[qlocal*3+2];
  const float Q = fmaf(qz, qz, fmaf(qy, qy, qx * qx));
  const float m2x = -2.0f * qx, m2y = -2.0f * qy, m2z = -2.0f * qz;
  const int selfpos = posof[qlocal];
  const int lo = (cnt * part) >> 3;
  const int hi = (cnt * (part + 1)) >> 3;

  float t[16];
  #pragma unroll
  for (int i = 0; i < 16; ++i) t[i] = 3.0e38f;

  const int len = hi - lo;
  const int ng = (len + 7) >> 3;
  for (int g = 0; g < ng; ++g) {
    const int base = lo + g * 8;
    float s[8];
    #pragma unroll
    for (int i = 0; i < 8; ++i) {
      int idx = base + i;
      float4 p = pts[idx];
      float d = fmaf(p.z, m2z, fmaf(p.y, m2y, fmaf(p.x, m2x, p.w)));
      d = (idx == selfpos) ? 3.0e38f : d;
      s[i] = (idx < hi) ? d : 3.0e38f;
    }
    #define CES(i,j) { float mn_ = VMIN(s[i], s[j]); float mx_ = VMAX(s[i], s[j]); s[i] = mn_; s[j] = mx_; }
    CES(0,1) CES(2,3) CES(4,5) CES(6,7)
    CES(0,2) CES(1,3) CES(4,6) CES(5,7)
    CES(1,2) CES(5,6)
    CES(0,4) CES(1,5) CES(2,6) CES(3,7)
    CES(2,4) CES(3,5)
    CES(1,2) CES(3,4) CES(5,6)
    #undef CES
    #pragma unroll
    for (int i = 0; i < 8; ++i) t[8 + i] = VMIN(t[8 + i], s[7 - i]);
    #define CET(i,j) { float mn_ = VMIN(t[i], t[j]); float mx_ = VMAX(t[i], t[j]); t[i] = mn_; t[j] = mx_; }
    CET(0,8) CET(1,9) CET(2,10) CET(3,11) CET(4,12) CET(5,13) CET(6,14) CET(7,15)
    CET(0,4) CET(1,5) CET(2,6)  CET(3,7)  CET(8,12) CET(9,13) CET(10,14) CET(11,15)
    CET(0,2) CET(1,3) CET(4,6)  CET(5,7)  CET(8,10) CET(9,11) CET(12,14) CET(13,15)
    CET(0,1) CET(2,3) CET(4,5)  CET(6,7)  CET(8,9)  CET(10,11) CET(12,13) CET(14,15)
    #undef CET
  }

  #pragma unroll
  for (int stepi = 0; stepi < 3; ++stepi) {
    const int step = 8 << stepi;
    float o_[16], m[16];
    #pragma unroll
    for (int i = 0; i < 16; ++i) o_[i] = __shfl(t[i], lane ^ step);
    #pragma unroll
    for (int i = 0; i < 16; ++i) m[i] = VMIN(t[i], o_[15 - i]);
    #define CE(i,jj) { float a_ = VMIN(m[i], m[jj]); float b_ = VMAX(m[i], m[jj]); m[i] = a_; m[jj] = b_; }
    CE(0,8) CE(1,9) CE(2,10) CE(3,11) CE(4,12) CE(5,13) CE(6,14) CE(7,15)
    CE(0,4) CE(1,5) CE(2,6)  CE(3,7)  CE(8,12) CE(9,13) CE(10,14) CE(11,15)
    CE(0,2) CE(1,3) CE(4,6)  CE(5,7)  CE(8,10) CE(9,11) CE(12,14) CE(13,15)
    CE(0,1) CE(2,3) CE(4,5)  CE(6,7)  CE(8,9)  CE(10,11) CE(12,13) CE(14,15)
    #undef CE
    #pragma unroll
    for (int i = 0; i < 16; ++i) t[i] = m[i];
  }

  if (part == 0) {
    int mq = read_mask(mask, mbase + qlocal, is8);
    float res[16];
    #pragma unroll
    for (int i = 0; i < 16; ++i) {
      float v = t[i];
      float d = (v > 1.0e37f) ? 24.0f : sqrtf(fmaxf(v + Q, 1e-12f));
      res[i] = mq ? d : -1.0f;   // -1 sentinel => output row forced to zero
    }
    float4* dst = (float4*)(dists + (size_t)(mbase + qlocal) * KTOP);
    float4 o0, o1, o2, o3;
    o0.x=res[0];  o0.y=res[1];  o0.z=res[2];  o0.w=res[3];
    o1.x=res[4];  o1.y=res[5];  o1.z=res[6];  o1.w=res[7];
    o2.x=res[8];  o2.y=res[9];  o2.z=res[10]; o2.w=res[11];
    o3.x=res[12]; o3.y=res[13]; o3.z=res[14]; o3.w=res[15];
    dst[0]=o0; dst[1]=o1; dst[2]=o2; dst[3]=o3;
  }
}

// ---------------- kernel 2: fused RBF + projection (bf16 MFMA) ----------------
// grid: QTOT/64 = 1024 blocks x 256 threads (4 waves), 2 blocks/CU (66.5 KB LDS).
// Block = 64 rows x ALL 256 cols: A gen'd exactly once (R11 gen'd it 4x).
// B re-read per k-slice from the bf16 prepass buffer (L2-resident, lane-linear
// coalesced 16B loads) -> live regs ~130, NO spill (the R5-R10 trap).
constexpr double SPd = 24.0 / 31.0;
constexpr double SP2d = SPd * SPd;
constexpr float ALPHA = (float)(-(SP2d / (SP2d + 1e-8)) * 1.4426950408889634);
constexpr float INV_SP = (float)(1.0 / SPd);

__device__ __forceinline__ void gen_cell(u32x4* Ah, int rowh, int s, float d0) {
  float d = (d0 < 0.f) ? 1.0e9f : d0;   // sentinel -> rbf == 0
  float u = d * INV_SP;
  float C1 = (-2.0f * ALPHA) * u;
  float C0 = ALPHA * u * u;
  #pragma unroll
  for (int c8 = 0; c8 < 4; ++c8) {
    u32x4 ch;
    #pragma unroll
    for (int q = 0; q < 4; ++q) {
      const int j0 = c8 * 8 + q * 2;
      float e0 = EXP2(fmaf(C1, (float)j0,       C0) + ALPHA * (float)(j0 * j0));
      float e1 = EXP2(fmaf(C1, (float)(j0 + 1), C0) + ALPHA * (float)((j0 + 1) * (j0 + 1)));
      ch[q] = pack2(e0, e1);
    }
    Ah[s * 65 + c8 * 16 + rowh] = ch;
  }
}

__global__ __launch_bounds__(256, 2) void rbf_gemm_kernel(
    const float* __restrict__ dists, const u32x4* __restrict__ Wb,
    float* __restrict__ out)
{
  __shared__ u32x4 A_sh[4][1040];   // [row-frag][s*65 + h*16 + row_lo]; 66560 B

  const int tid = threadIdx.x;
  const int lane = tid & 63;
  const int wv = tid >> 6;           // 0..3
  const int qbase = blockIdx.x * 64;

  // gen: 4 cells/thread; cell = (row, slot), cellid = tid + 256*i
  const size_t dbase = (size_t)qbase * KTOP;
  float dv[4];
  #pragma unroll
  for (int i = 0; i < 4; ++i) dv[i] = dists[dbase + tid + 256 * i];
  #pragma unroll
  for (int i = 0; i < 4; ++i) {
    int cellid = tid + 256 * i;
    int row = cellid >> 4, slot = cellid & 15;
    gen_cell(&A_sh[row >> 4][0], row & 15, slot, dv[i]);
  }
  __syncthreads();

  f32x4 acc[4][4];   // [row-frag][col-set]
  #pragma unroll
  for (int rf = 0; rf < 4; ++rf)
    #pragma unroll
    for (int e = 0; e < 4; ++e) acc[rf][e] = (f32x4){0.f, 0.f, 0.f, 0.f};

  #pragma unroll
  for (int s = 0; s < 16; ++s) {
    s16x8 a[4], b[4];
    #pragma unroll
    for (int rf = 0; rf < 4; ++rf) {
      u32x4 ra = A_sh[rf][s * 65 + lane];
      __builtin_memcpy(&a[rf], &ra, sizeof(ra));
    }
    #pragma unroll
    for (int e = 0; e < 4; ++e) {
      u32x4 rb = Wb[(size_t)((e * 4 + wv) * 16 + s) * 64 + lane];
      __builtin_memcpy(&b[e], &rb, sizeof(rb));
    }
    #pragma unroll
    for (int rf = 0; rf < 4; ++rf)
      #pragma unroll
      for (int e = 0; e < 4; ++e)
        acc[rf][e] = __builtin_amdgcn_mfma_f32_16x16x32_bf16(a[rf], b[e], acc[rf][e], 0, 0, 0);
  }

  // D layout: col = lane&15, row = (lane>>4)*4 + reg. Clean scalar store
  // pattern (16 adjacent lanes = 64B runs), proven exact-WRITE in R1/R11.
  const int rb_ = (lane >> 4) * 4;
  #pragma unroll
  for (int rf = 0; rf < 4; ++rf) {
    #pragma unroll
    for (int e = 0; e < 4; ++e) {
      const int col = e * 64 + wv * 16 + (lane & 15);
      #pragma unroll
      for (int r = 0; r < 4; ++r)
        out[(size_t)(qbase + rf * 16 + rb_ + r) * ODIM + col] = acc[rf][e][r];
    }
  }
}

extern "C" void kernel_launch(void* const* d_in, const int* in_sizes, int n_in,
                              void* d_out, int out_size, void* d_ws, size_t ws_size,
                              hipStream_t stream) {
  const float* coords = (const float*)d_in[0];
  const void* mask = d_in[1];
  const float* W = (const float*)d_in[2];
  float* out = (float*)d_out;
  float* dists = (float*)d_ws;                       // 4 MB
  u32x4* Wb = (u32x4*)((char*)d_ws + (QTOT * KTOP * 4));  // 256 KB bf16 W frags

  hipLaunchKernelGGL(wconv_kernel, dim3(16), dim3(256), 0, stream, W, Wb);
  hipLaunchKernelGGL(topk_kernel, dim3(QTOT / 32), dim3(256), 0, stream,
                     coords, mask, dists);
  hipLaunchKernelGGL(rbf_gemm_kernel, dim3(QTOT / 64), dim3(256), 0, stream,
                     dists, Wb, out);
}

// Round 13
// 63.687 us; speedup vs baseline: 2.1444x; 1.1130x over previous
//
#include <hip/hip_runtime.h>
#include <hip/hip_bf16.h>
#include <math.h>

#define MDIM 1024
#define QTOT 65536
#define KTOP 16
#define ODIM 256
#define FDIM 512

typedef float f32x4 __attribute__((ext_vector_type(4)));
typedef short s16x8 __attribute__((ext_vector_type(8)));
typedef unsigned u32x4 __attribute__((ext_vector_type(4)));

#if __has_builtin(__builtin_amdgcn_exp2f)
#define EXP2(x) __builtin_amdgcn_exp2f(x)
#else
#define EXP2(x) exp2f(x)
#endif

// pinned single-instruction min/max
#define VMIN(a,b)    ({float r_; asm("v_min_f32 %0,%1,%2":"=v"(r_):"v"(a),"v"(b)); r_;})
#define VMAX(a,b)    ({float r_; asm("v_max_f32 %0,%1,%2":"=v"(r_):"v"(a),"v"(b)); r_;})

__device__ __forceinline__ int read_mask(const void* m, int i, bool is8) {
  return is8 ? (int)((const unsigned char*)m)[i] : ((const int*)m)[i];
}

__device__ __forceinline__ unsigned pack2(float lo, float hi) {
  __hip_bfloat162 h = __float22bfloat162_rn(make_float2(lo, hi));
  unsigned u;
  __builtin_memcpy(&u, &h, sizeof(u));
  return u;
}

// ---------------- kernel 0: W fp32 -> bf16 fragment-layout prepass ----------
// Wb[(cg*16+s)*64 + l]: 8 bf16 = W[col = cg*16 + (l&15)][s*32 + (l>>4)*8 ..+8]
__global__ __launch_bounds__(256) void wconv_kernel(
    const float* __restrict__ W, u32x4* __restrict__ Wb)
{
  int slot = blockIdx.x * 256 + threadIdx.x;   // 0..16383
  int cg = slot >> 10;
  int rem = slot & 1023;
  int s = rem >> 6, l = rem & 63;
  int col = cg * 16 + (l & 15);
  int kk = s * 32 + (l >> 4) * 8;
  const float4* p = (const float4*)(W + (size_t)col * FDIM + kk);
  float4 a = p[0], b = p[1];
  u32x4 u0;
  u0[0] = pack2(a.x, a.y); u0[1] = pack2(a.z, a.w);
  u0[2] = pack2(b.x, b.y); u0[3] = pack2(b.z, b.w);
  Wb[(size_t)(cg * 16 + s) * 64 + l] = u0;
}

// ---------------- kernel 1: top-16 neighbor distances ----------------
// grid: QTOT/32 blocks x 256 threads, 8 blocks/CU. Compacted array padded to
// x64 with +inf sentinels -> all sort-groups full (no tail check).
__global__ __launch_bounds__(256, 8) void topk_kernel(
    const float* __restrict__ coords, const void* __restrict__ mask,
    float* __restrict__ dists)
{
  __shared__ float4 pts[MDIM];
  __shared__ short posof[MDIM];
  __shared__ int s_cnt;
  __shared__ int s_is8;
  const int tid = threadIdx.x;
  const int lane = tid & 63;
  const int wv = tid >> 6;
  const int bid = blockIdx.x;
  const int batch = bid >> 5;      // 32 blocks per batch
  const int qchunk = bid & 31;

  if (tid == 0) { s_cnt = 0; s_is8 = 0; }
  __syncthreads();
  { // mask dtype detection: int32 0/1 words vs packed int8 bools
    unsigned w = ((const unsigned*)mask)[tid & 255];
    if (w > 1u) atomicOr(&s_is8, 1);
  }
  __syncthreads();
  const bool is8 = (s_is8 != 0);

  const float* cb = coords + (size_t)batch * MDIM * 3;
  const int mbase = batch * MDIM;

  // compact valid atoms into LDS: (x,y,z,|p|^2)
  #pragma unroll
  for (int r = 0; r < 4; ++r) {
    int a = r * 256 + tid;
    int v = read_mask(mask, mbase + a, is8);
    float x = cb[a*3+0], y = cb[a*3+1], z = cb[a*3+2];
    float S = fmaf(z, z, fmaf(y, y, x * x));
    unsigned long long bal = __ballot(v != 0);
    int base = 0;
    if (lane == 0) base = atomicAdd(&s_cnt, __popcll(bal));
    base = __shfl(base, 0);
    int pos = base + __popcll(bal & ((1ull << lane) - 1ull));
    if (v) {
      float4 p; p.x = x; p.y = y; p.z = z; p.w = S;
      pts[pos] = p;
    }
    posof[a] = (short)(v ? pos : -1);
  }
  __syncthreads();
  const int cnt = s_cnt;
  const int cntP = (cnt + 63) & ~63;   // pad to x64 (<= MDIM)
  for (int i = cnt + tid; i < cntP; i += 256) {
    float4 p; p.x = 0.f; p.y = 0.f; p.z = 0.f; p.w = 3.0e38f;  // d' = +huge
    pts[i] = p;
  }
  __syncthreads();

  // 8 lanes per query: lane = qi + 8*part
  const int qi = lane & 7;
  const int part = lane >> 3;
  const int qlocal = qchunk * 32 + wv * 8 + qi;
  const float qx = cb[qlocal*3+0], qy = cb[qlocal*3+1], qz = cb[qlocal*3+2];
  const float Q = fmaf(qz, qz, fmaf(qy, qy, qx * qx));
  const float m2x = -2.0f * qx, m2y = -2.0f * qy, m2z = -2.0f * qz;
  const int selfpos = posof[qlocal];
  const int lo = (cntP * part) >> 3;     // multiple of 8
  const int ng = cntP >> 6;              // full groups per part

  float t[16];
  #pragma unroll
  for (int i = 0; i < 16; ++i) t[i] = 3.0e38f;

  for (int g = 0; g < ng; ++g) {
    const int base = lo + g * 8;
    float s[8];
    #pragma unroll
    for (int i = 0; i < 8; ++i) {
      int idx = base + i;
      float4 p = pts[idx];
      // d' = |p|^2 - 2 q.p  (= d^2 - Q, order-preserving)
      float d = fmaf(p.z, m2z, fmaf(p.y, m2y, fmaf(p.x, m2x, p.w)));
      s[i] = (idx == selfpos) ? 3.0e38f : d;   // exclude self
    }
    // Batcher sort-8 (19 CE)
    #define CES(i,j) { float mn_ = VMIN(s[i], s[j]); float mx_ = VMAX(s[i], s[j]); s[i] = mn_; s[j] = mx_; }
    CES(0,1) CES(2,3) CES(4,5) CES(6,7)
    CES(0,2) CES(1,3) CES(4,6) CES(5,7)
    CES(1,2) CES(5,6)
    CES(0,4) CES(1,5) CES(2,6) CES(3,7)
    CES(2,4) CES(3,5)
    CES(1,2) CES(3,4) CES(5,6)
    #undef CES
    // half-clean: t[8..15] vs reversed s -> bitonic, holds 16 smallest
    #pragma unroll
    for (int i = 0; i < 8; ++i) t[8 + i] = VMIN(t[8 + i], s[7 - i]);
    // bitonic clean of 16
    #define CET(i,j) { float mn_ = VMIN(t[i], t[j]); float mx_ = VMAX(t[i], t[j]); t[i] = mn_; t[j] = mx_; }
    CET(0,8) CET(1,9) CET(2,10) CET(3,11) CET(4,12) CET(5,13) CET(6,14) CET(7,15)
    CET(0,4) CET(1,5) CET(2,6)  CET(3,7)  CET(8,12) CET(9,13) CET(10,14) CET(11,15)
    CET(0,2) CET(1,3) CET(4,6)  CET(5,7)  CET(8,10) CET(9,11) CET(12,14) CET(13,15)
    CET(0,1) CET(2,3) CET(4,5)  CET(6,7)  CET(8,9)  CET(10,11) CET(12,13) CET(14,15)
    #undef CET
  }

  // merge the 8 part-lists: bitonic merges with partners ^8, ^16, ^32
  #pragma unroll
  for (int stepi = 0; stepi < 3; ++stepi) {
    const int step = 8 << stepi;
    float o_[16], m[16];
    #pragma unroll
    for (int i = 0; i < 16; ++i) o_[i] = __shfl(t[i], lane ^ step);
    #pragma unroll
    for (int i = 0; i < 16; ++i) m[i] = VMIN(t[i], o_[15 - i]);
    #define CE(i,jj) { float a_ = VMIN(m[i], m[jj]); float b_ = VMAX(m[i], m[jj]); m[i] = a_; m[jj] = b_; }
    CE(0,8) CE(1,9) CE(2,10) CE(3,11) CE(4,12) CE(5,13) CE(6,14) CE(7,15)
    CE(0,4) CE(1,5) CE(2,6)  CE(3,7)  CE(8,12) CE(9,13) CE(10,14) CE(11,15)
    CE(0,2) CE(1,3) CE(4,6)  CE(5,7)  CE(8,10) CE(9,11) CE(12,14) CE(13,15)
    CE(0,1) CE(2,3) CE(4,5)  CE(6,7)  CE(8,9)  CE(10,11) CE(12,13) CE(14,15)
    #undef CE
    #pragma unroll
    for (int i = 0; i < 16; ++i) t[i] = m[i];
  }

  if (part == 0) {
    int mq = read_mask(mask, mbase + qlocal, is8);
    float res[16];
    #pragma unroll
    for (int i = 0; i < 16; ++i) {
      float v = t[i];
      float d = (v > 1.0e37f) ? 24.0f : sqrtf(fmaxf(v + Q, 1e-12f)); // pad -> MAX_DIST
      res[i] = mq ? d : -1.0f;   // -1 sentinel => output row forced to zero
    }
    float4* dst = (float4*)(dists + (size_t)(mbase + qlocal) * KTOP);
    float4 o0, o1, o2, o3;
    o0.x=res[0];  o0.y=res[1];  o0.z=res[2];  o0.w=res[3];
    o1.x=res[4];  o1.y=res[5];  o1.z=res[6];  o1.w=res[7];
    o2.x=res[8];  o2.y=res[9];  o2.z=res[10]; o2.w=res[11];
    o3.x=res[12]; o3.y=res[13]; o3.z=res[14]; o3.w=res[15];
    dst[0]=o0; dst[1]=o1; dst[2]=o2; dst[3]=o3;
  }
}

// ---------------- kernel 2: fused RBF + projection (bf16 MFMA) ----------------
// grid: QTOT/64 = 1024 blocks x 512 threads (8 waves), 2 blocks/CU (66.5 KB LDS)
// -> 4 waves/SIMD. Block = 64 rows x ALL 256 cols (A gen'd once). Wave owns
// col-groups {wv, 8+wv}; B re-read per k-slice from bf16 prepass buffer with
// 1-deep prefetch (hides ~200cyc L2 latency). acc[4][2]+b regs ~100 (no spill).
constexpr double SPd = 24.0 / 31.0;
constexpr double SP2d = SPd * SPd;
constexpr float ALPHA = (float)(-(SP2d / (SP2d + 1e-8)) * 1.4426950408889634);
constexpr float INV_SP = (float)(1.0 / SPd);

__device__ __forceinline__ void gen_cell(u32x4* Ah, int rowh, int s, float d0) {
  float d = (d0 < 0.f) ? 1.0e9f : d0;   // sentinel -> rbf == 0
  float u = d * INV_SP;
  float C1 = (-2.0f * ALPHA) * u;
  float C0 = ALPHA * u * u;
  #pragma unroll
  for (int c8 = 0; c8 < 4; ++c8) {
    u32x4 ch;
    #pragma unroll
    for (int q = 0; q < 4; ++q) {
      const int j0 = c8 * 8 + q * 2;
      float e0 = EXP2(fmaf(C1, (float)j0,       C0) + ALPHA * (float)(j0 * j0));
      float e1 = EXP2(fmaf(C1, (float)(j0 + 1), C0) + ALPHA * (float)((j0 + 1) * (j0 + 1)));
      ch[q] = pack2(e0, e1);
    }
    Ah[s * 65 + c8 * 16 + rowh] = ch;
  }
}

__global__ __launch_bounds__(512, 4) void rbf_gemm_kernel(
    const float* __restrict__ dists, const u32x4* __restrict__ Wb,
    float* __restrict__ out)
{
  __shared__ u32x4 A_sh[4][1040];   // [row-frag][s*65 + h*16 + row_lo]; 66560 B

  const int tid = threadIdx.x;      // 0..511
  const int lane = tid & 63;
  const int wv = tid >> 6;          // 0..7
  const int qbase = blockIdx.x * 64;
  const size_t dbase = (size_t)qbase * KTOP;

  // gen: 2 cells/thread; cell = row*16 + slot
  float dv0 = dists[dbase + tid];
  float dv1 = dists[dbase + 512 + tid];
  {
    const int c0 = tid, c1 = tid + 512;
    gen_cell(&A_sh[c0 >> 8][0], (c0 >> 4) & 15, c0 & 15, dv0);
    gen_cell(&A_sh[c1 >> 8][0], (c1 >> 4) & 15, c1 & 15, dv1);
  }
  __syncthreads();

  f32x4 acc[4][2];
  #pragma unroll
  for (int rf = 0; rf < 4; ++rf)
    #pragma unroll
    for (int e = 0; e < 2; ++e) acc[rf][e] = (f32x4){0.f, 0.f, 0.f, 0.f};

  u32x4 bcur[2], bnxt[2];
  #pragma unroll
  for (int e = 0; e < 2; ++e)
    bcur[e] = Wb[(size_t)((e * 8 + wv) * 16) * 64 + lane];

  #pragma unroll
  for (int s = 0; s < 16; ++s) {
    if (s < 15) {
      #pragma unroll
      for (int e = 0; e < 2; ++e)
        bnxt[e] = Wb[(size_t)((e * 8 + wv) * 16 + s + 1) * 64 + lane];
    }
    s16x8 a[4], b[2];
    #pragma unroll
    for (int rf = 0; rf < 4; ++rf) {
      u32x4 ra = A_sh[rf][s * 65 + lane];
      __builtin_memcpy(&a[rf], &ra, sizeof(ra));
    }
    #pragma unroll
    for (int e = 0; e < 2; ++e) __builtin_memcpy(&b[e], &bcur[e], sizeof(u32x4));
    #pragma unroll
    for (int rf = 0; rf < 4; ++rf)
      #pragma unroll
      for (int e = 0; e < 2; ++e)
        acc[rf][e] = __builtin_amdgcn_mfma_f32_16x16x32_bf16(a[rf], b[e], acc[rf][e], 0, 0, 0);
    #pragma unroll
    for (int e = 0; e < 2; ++e) bcur[e] = bnxt[e];
  }

  // D layout: col = lane&15, row = (lane>>4)*4 + reg. Clean scalar pattern
  // (16 adjacent lanes = 64B runs) — WRITE_SIZE-exact in R1/R11.
  const int rb_ = (lane >> 4) * 4;
  #pragma unroll
  for (int rf = 0; rf < 4; ++rf) {
    #pragma unroll
    for (int e = 0; e < 2; ++e) {
      const int col = (e * 8 + wv) * 16 + (lane & 15);
      #pragma unroll
      for (int r = 0; r < 4; ++r)
        out[(size_t)(qbase + rf * 16 + rb_ + r) * ODIM + col] = acc[rf][e][r];
    }
  }
}

extern "C" void kernel_launch(void* const* d_in, const int* in_sizes, int n_in,
                              void* d_out, int out_size, void* d_ws, size_t ws_size,
                              hipStream_t stream) {
  const float* coords = (const float*)d_in[0];
  const void* mask = d_in[1];
  const float* W = (const float*)d_in[2];
  float* out = (float*)d_out;
  float* dists = (float*)d_ws;                            // 4 MB
  u32x4* Wb = (u32x4*)((char*)d_ws + (QTOT * KTOP * 4));  // 256 KB bf16 W frags

  hipLaunchKernelGGL(wconv_kernel, dim3(64), dim3(256), 0, stream, W, Wb);
  hipLaunchKernelGGL(topk_kernel, dim3(QTOT / 32), dim3(256), 0, stream,
                     coords, mask, dists);
  hipLaunchKernelGGL(rbf_gemm_kernel, dim3(QTOT / 64), dim3(512), 0, stream,
                     dists, Wb, out);
}

// Round 15
// 55.141 us; speedup vs baseline: 2.4768x; 1.1550x over previous
//
#include <hip/hip_runtime.h>
#include <hip/hip_bf16.h>
#include <math.h>

#define MDIM 1024
#define QTOT 65536
#define KTOP 16
#define ODIM 256
#define FDIM 512

typedef float f32x4 __attribute__((ext_vector_type(4)));
typedef short s16x8 __attribute__((ext_vector_type(8)));
typedef unsigned u32x4 __attribute__((ext_vector_type(4)));

#if __has_builtin(__builtin_amdgcn_exp2f)
#define EXP2(x) __builtin_amdgcn_exp2f(x)
#else
#define EXP2(x) exp2f(x)
#endif

// pinned single-instruction min/max
#define VMIN(a,b)    ({float r_; asm("v_min_f32 %0,%1,%2":"=v"(r_):"v"(a),"v"(b)); r_;})
#define VMAX(a,b)    ({float r_; asm("v_max_f32 %0,%1,%2":"=v"(r_):"v"(a),"v"(b)); r_;})

__device__ __forceinline__ int read_mask(const void* m, int i, bool is8) {
  return is8 ? (int)((const unsigned char*)m)[i] : ((const int*)m)[i];
}

__device__ __forceinline__ unsigned pack2(float lo, float hi) {
  __hip_bfloat162 h = __float22bfloat162_rn(make_float2(lo, hi));
  unsigned u;
  __builtin_memcpy(&u, &h, sizeof(u));
  return u;
}

// ---------------- kernel 0: W fp32 -> bf16 fragment-layout prepass ----------
// Wb[(cg*16+s)*64 + l]: 8 bf16 = W[col = cg*16 + (l&15)][s*32 + (l>>4)*8 ..+8]
__global__ __launch_bounds__(256) void wconv_kernel(
    const float* __restrict__ W, u32x4* __restrict__ Wb)
{
  int slot = blockIdx.x * 256 + threadIdx.x;   // 0..16383
  int cg = slot >> 10;
  int rem = slot & 1023;
  int s = rem >> 6, l = rem & 63;
  int col = cg * 16 + (l & 15);
  int kk = s * 32 + (l >> 4) * 8;
  const float4* p = (const float4*)(W + (size_t)col * FDIM + kk);
  float4 a = p[0], b = p[1];
  u32x4 u0;
  u0[0] = pack2(a.x, a.y); u0[1] = pack2(a.z, a.w);
  u0[2] = pack2(b.x, b.y); u0[3] = pack2(b.z, b.w);
  Wb[(size_t)(cg * 16 + s) * 64 + l] = u0;
}

// ---------------- fused kernel: top-16 -> RBF -> projection ----------------
// grid: QTOT/32 = 2048 blocks x 256 threads (4 waves), 4 blocks/CU (35.5 KB).
// Phase 1: per-query top-16 (8 lanes/query, sort8+bitonic merge) -> dvals LDS.
// Phase 2: RBF A-tile gen into the SAME LDS (union with pts; selection done),
//          MFMA 32 rows x 256 cols (acc[2][4], B prefetched from L2-resident
//          Wb), clean scalar stores (16 adjacent lanes = 64B runs).
constexpr double SPd = 24.0 / 31.0;
constexpr double SP2d = SPd * SPd;
constexpr float ALPHA = (float)(-(SP2d / (SP2d + 1e-8)) * 1.4426950408889634);
constexpr float INV_SP = (float)(1.0 / SPd);

__device__ __forceinline__ void gen_cell(u32x4* Ab, int rf, int rowlo, int s, float d0) {
  float d = (d0 < 0.f) ? 1.0e9f : d0;   // sentinel -> rbf == 0
  float u = d * INV_SP;
  float C1 = (-2.0f * ALPHA) * u;
  float C0 = ALPHA * u * u;
  #pragma unroll
  for (int c8 = 0; c8 < 4; ++c8) {
    u32x4 ch;
    #pragma unroll
    for (int q = 0; q < 4; ++q) {
      const int j0 = c8 * 8 + q * 2;
      float e0 = EXP2(fmaf(C1, (float)j0,       C0) + ALPHA * (float)(j0 * j0));
      float e1 = EXP2(fmaf(C1, (float)(j0 + 1), C0) + ALPHA * (float)((j0 + 1) * (j0 + 1)));
      ch[q] = pack2(e0, e1);
    }
    Ab[rf * 1040 + s * 65 + c8 * 16 + rowlo] = ch;
  }
}

__global__ __launch_bounds__(256, 4) void fused_kernel(
    const float* __restrict__ coords, const void* __restrict__ mask,
    const u32x4* __restrict__ Wb, float* __restrict__ out)
{
  // raw LDS: phase 1 = pts float4[1024] (16384B) + posof short[1024] (2048B);
  // phase 2 = A tile u32x4[2][1040] (33280B). Union -> 33280B.
  __shared__ __align__(16) char raw[33280];
  __shared__ float dvals[32][17];
  __shared__ int s_cnt;
  __shared__ int s_is8;

  float4* pts = (float4*)raw;
  short* posof = (short*)(raw + 16384);
  u32x4* Ab = (u32x4*)raw;

  const int tid = threadIdx.x;
  const int lane = tid & 63;
  const int wv = tid >> 6;
  const int bid = blockIdx.x;
  const int batch = bid >> 5;      // 32 blocks per batch (32 queries each)
  const int qchunk = bid & 31;

  if (tid == 0) { s_cnt = 0; s_is8 = 0; }
  __syncthreads();
  { // mask dtype detection: int32 0/1 words vs packed int8 bools
    unsigned w = ((const unsigned*)mask)[tid & 255];
    if (w > 1u) atomicOr(&s_is8, 1);
  }
  __syncthreads();
  const bool is8 = (s_is8 != 0);

  const float* cb = coords + (size_t)batch * MDIM * 3;
  const int mbase = batch * MDIM;

  // compact valid atoms into LDS: (x,y,z,|p|^2)
  #pragma unroll
  for (int r = 0; r < 4; ++r) {
    int a = r * 256 + tid;
    int v = read_mask(mask, mbase + a, is8);
    float x = cb[a*3+0], y = cb[a*3+1], z = cb[a*3+2];
    float S = fmaf(z, z, fmaf(y, y, x * x));
    unsigned long long bal = __ballot(v != 0);
    int base = 0;
    if (lane == 0) base = atomicAdd(&s_cnt, __popcll(bal));
    base = __shfl(base, 0);
    int pos = base + __popcll(bal & ((1ull << lane) - 1ull));
    if (v) {
      float4 p; p.x = x; p.y = y; p.z = z; p.w = S;
      pts[pos] = p;
    }
    posof[a] = (short)(v ? pos : -1);
  }
  __syncthreads();
  const int cnt = s_cnt;
  const int cntP = (cnt + 63) & ~63;   // pad to x64 (<= MDIM)
  for (int i = cnt + tid; i < cntP; i += 256) {
    float4 p; p.x = 0.f; p.y = 0.f; p.z = 0.f; p.w = 3.0e38f;  // d' = +huge
    pts[i] = p;
  }
  __syncthreads();

  // 8 lanes per query: lane = qi + 8*part; query-in-block qlo = wv*8 + qi
  const int qi = lane & 7;
  const int part = lane >> 3;
  const int qlo = wv * 8 + qi;
  const int qlocal = qchunk * 32 + qlo;
  const float qx = cb[qlocal*3+0], qy = cb[qlocal*3+1], qz = cb[qlocal*3+2];
  const float Q = fmaf(qz, qz, fmaf(qy, qy, qx * qx));
  const float m2x = -2.0f * qx, m2y = -2.0f * qy, m2z = -2.0f * qz;
  const int selfpos = posof[qlocal];
  const int lo = (cntP * part) >> 3;     // multiple of 8
  const int ng = cntP >> 6;              // full groups per part

  float t[16];
  #pragma unroll
  for (int i = 0; i < 16; ++i) t[i] = 3.0e38f;

  for (int g = 0; g < ng; ++g) {
    const int base = lo + g * 8;
    float s[8];
    #pragma unroll
    for (int i = 0; i < 8; ++i) {
      int idx = base + i;
      float4 p = pts[idx];
      // d' = |p|^2 - 2 q.p  (= d^2 - Q, order-preserving)
      float d = fmaf(p.z, m2z, fmaf(p.y, m2y, fmaf(p.x, m2x, p.w)));
      s[i] = (idx == selfpos) ? 3.0e38f : d;   // exclude self
    }
    // Batcher sort-8 (19 CE)
    #define CES(i,j) { float mn_ = VMIN(s[i], s[j]); float mx_ = VMAX(s[i], s[j]); s[i] = mn_; s[j] = mx_; }
    CES(0,1) CES(2,3) CES(4,5) CES(6,7)
    CES(0,2) CES(1,3) CES(4,6) CES(5,7)
    CES(1,2) CES(5,6)
    CES(0,4) CES(1,5) CES(2,6) CES(3,7)
    CES(2,4) CES(3,5)
    CES(1,2) CES(3,4) CES(5,6)
    #undef CES
    // half-clean: t[8..15] vs reversed s -> bitonic, holds 16 smallest
    #pragma unroll
    for (int i = 0; i < 8; ++i) t[8 + i] = VMIN(t[8 + i], s[7 - i]);
    // bitonic clean of 16
    #define CET(i,j) { float mn_ = VMIN(t[i], t[j]); float mx_ = VMAX(t[i], t[j]); t[i] = mn_; t[j] = mx_; }
    CET(0,8) CET(1,9) CET(2,10) CET(3,11) CET(4,12) CET(5,13) CET(6,14) CET(7,15)
    CET(0,4) CET(1,5) CET(2,6)  CET(3,7)  CET(8,12) CET(9,13) CET(10,14) CET(11,15)
    CET(0,2) CET(1,3) CET(4,6)  CET(5,7)  CET(8,10) CET(9,11) CET(12,14) CET(13,15)
    CET(0,1) CET(2,3) CET(4,5)  CET(6,7)  CET(8,9)  CET(10,11) CET(12,13) CET(14,15)
    #undef CET
  }

  // merge the 8 part-lists: bitonic merges with partners ^8, ^16, ^32
  #pragma unroll
  for (int stepi = 0; stepi < 3; ++stepi) {
    const int step = 8 << stepi;
    float o_[16], m[16];
    #pragma unroll
    for (int i = 0; i < 16; ++i) o_[i] = __shfl(t[i], lane ^ step);
    #pragma unroll
    for (int i = 0; i < 16; ++i) m[i] = VMIN(t[i], o_[15 - i]);
    #define CE(i,jj) { float a_ = VMIN(m[i], m[jj]); float b_ = VMAX(m[i], m[jj]); m[i] = a_; m[jj] = b_; }
    CE(0,8) CE(1,9) CE(2,10) CE(3,11) CE(4,12) CE(5,13) CE(6,14) CE(7,15)
    CE(0,4) CE(1,5) CE(2,6)  CE(3,7)  CE(8,12) CE(9,13) CE(10,14) CE(11,15)
    CE(0,2) CE(1,3) CE(4,6)  CE(5,7)  CE(8,10) CE(9,11) CE(12,14) CE(13,15)
    CE(0,1) CE(2,3) CE(4,5)  CE(6,7)  CE(8,9)  CE(10,11) CE(12,13) CE(14,15)
    #undef CE
    #pragma unroll
    for (int i = 0; i < 16; ++i) t[i] = m[i];
  }

  if (part == 0) {
    int mq = read_mask(mask, mbase + qlocal, is8);
    #pragma unroll
    for (int i = 0; i < 16; ++i) {
      float v = t[i];
      float d = (v > 1.0e37f) ? 24.0f : sqrtf(fmaxf(v + Q, 1e-12f)); // pad -> MAX_DIST
      dvals[qlo][i] = mq ? d : -1.0f;   // -1 sentinel => zero output row
    }
  }
  __syncthreads();   // dvals ready; pts/posof dead -> LDS reused as A tile

  // ---- phase 2: RBF A-gen (2 cells/thread) ----
  #pragma unroll
  for (int i = 0; i < 2; ++i) {
    int cellid = tid + 256 * i;          // 0..511
    int row = cellid >> 4, slot = cellid & 15;
    gen_cell(Ab, row >> 4, row & 15, slot, dvals[row][slot]);
  }
  __syncthreads();

  // ---- phase 3: MFMA 32 rows x 256 cols; wave owns col-groups {4e+wv} ----
  f32x4 acc[2][4];
  #pragma unroll
  for (int rf = 0; rf < 2; ++rf)
    #pragma unroll
    for (int e = 0; e < 4; ++e) acc[rf][e] = (f32x4){0.f, 0.f, 0.f, 0.f};

  u32x4 bcur[4], bnxt[4];
  #pragma unroll
  for (int e = 0; e < 4; ++e)
    bcur[e] = Wb[(size_t)((e * 4 + wv) * 16) * 64 + lane];

  #pragma unroll
  for (int s = 0; s < 16; ++s) {
    if (s < 15) {
      #pragma unroll
      for (int e = 0; e < 4; ++e)
        bnxt[e] = Wb[(size_t)((e * 4 + wv) * 16 + s + 1) * 64 + lane];
    }
    s16x8 a[2], b[4];
    #pragma unroll
    for (int rf = 0; rf < 2; ++rf) {
      u32x4 ra = Ab[rf * 1040 + s * 65 + lane];
      __builtin_memcpy(&a[rf], &ra, sizeof(ra));
    }
    #pragma unroll
    for (int e = 0; e < 4; ++e) __builtin_memcpy(&b[e], &bcur[e], sizeof(u32x4));
    #pragma unroll
    for (int rf = 0; rf < 2; ++rf)
      #pragma unroll
      for (int e = 0; e < 4; ++e)
        acc[rf][e] = __builtin_amdgcn_mfma_f32_16x16x32_bf16(a[rf], b[e], acc[rf][e], 0, 0, 0);
    #pragma unroll
    for (int e = 0; e < 4; ++e) bcur[e] = bnxt[e];
  }

  // D layout: col = lane&15, row = (lane>>4)*4 + reg. Clean scalar pattern
  // (16 adjacent lanes = 64B runs) — WRITE_SIZE-exact in R1/R11.
  const int qbase = mbase + qchunk * 32;
  const int rb_ = (lane >> 4) * 4;
  #pragma unroll
  for (int rf = 0; rf < 2; ++rf) {
    #pragma unroll
    for (int e = 0; e < 4; ++e) {
      const int col = (e * 4 + wv) * 16 + (lane & 15);
      #pragma unroll
      for (int r = 0; r < 4; ++r)
        out[(size_t)(qbase + rf * 16 + rb_ + r) * ODIM + col] = acc[rf][e][r];
    }
  }
}

extern "C" void kernel_launch(void* const* d_in, const int* in_sizes, int n_in,
                              void* d_out, int out_size, void* d_ws, size_t ws_size,
                              hipStream_t stream) {
  const float* coords = (const float*)d_in[0];
  const void* mask = d_in[1];
  const float* W = (const float*)d_in[2];
  float* out = (float*)d_out;
  u32x4* Wb = (u32x4*)d_ws;   // 256 KB bf16 W fragments

  hipLaunchKernelGGL(wconv_kernel, dim3(64), dim3(256), 0, stream, W, Wb);
  hipLaunchKernelGGL(fused_kernel, dim3(QTOT / 32), dim3(256), 0, stream,
                     coords, mask, Wb, out);
}

// Round 16
// 54.942 us; speedup vs baseline: 2.4857x; 1.0036x over previous
//
#include <hip/hip_runtime.h>
#include <hip/hip_bf16.h>
#include <math.h>

#define MDIM 1024
#define QTOT 65536
#define KTOP 16
#define ODIM 256
#define FDIM 512

typedef float f32x4 __attribute__((ext_vector_type(4)));
typedef short s16x8 __attribute__((ext_vector_type(8)));
typedef unsigned u32x4 __attribute__((ext_vector_type(4)));

#if __has_builtin(__builtin_amdgcn_exp2f)
#define EXP2(x) __builtin_amdgcn_exp2f(x)
#else
#define EXP2(x) exp2f(x)
#endif

// pinned single-instruction min/max
#define VMIN(a,b)    ({float r_; asm("v_min_f32 %0,%1,%2":"=v"(r_):"v"(a),"v"(b)); r_;})
#define VMAX(a,b)    ({float r_; asm("v_max_f32 %0,%1,%2":"=v"(r_):"v"(a),"v"(b)); r_;})

__device__ __forceinline__ int read_mask(const void* m, int i, bool is8) {
  return is8 ? (int)((const unsigned char*)m)[i] : ((const int*)m)[i];
}

__device__ __forceinline__ unsigned pack2(float lo, float hi) {
  __hip_bfloat162 h = __float22bfloat162_rn(make_float2(lo, hi));
  unsigned u;
  __builtin_memcpy(&u, &h, sizeof(u));
  return u;
}

// ---------------- kernel 0: W fp32 -> bf16 fragment-layout prepass ----------
// Wb[(cg*16+s)*64 + l]: 8 bf16 = W[col = cg*16 + (l&15)][s*32 + (l>>4)*8 ..+8]
__global__ __launch_bounds__(256) void wconv_kernel(
    const float* __restrict__ W, u32x4* __restrict__ Wb)
{
  int slot = blockIdx.x * 256 + threadIdx.x;   // 0..16383
  int cg = slot >> 10;
  int rem = slot & 1023;
  int s = rem >> 6, l = rem & 63;
  int col = cg * 16 + (l & 15);
  int kk = s * 32 + (l >> 4) * 8;
  const float4* p = (const float4*)(W + (size_t)col * FDIM + kk);
  float4 a = p[0], b = p[1];
  u32x4 u0;
  u0[0] = pack2(a.x, a.y); u0[1] = pack2(a.z, a.w);
  u0[2] = pack2(b.x, b.y); u0[3] = pack2(b.z, b.w);
  Wb[(size_t)(cg * 16 + s) * 64 + l] = u0;
}

// ---------------- fused kernel: top-16 -> RBF -> projection ----------------
// grid: QTOT/64 = 1024 blocks x 512 threads (8 waves), 2 blocks/CU (71 KB LDS).
// Block = 64 queries of one batch. Phase 1: top-16 (8 lanes/query, sort8 +
// bitonic merge; candidate loads ROTATED per part -> conflict-free banks).
// Phase 2: RBF A-gen into union'd LDS. Phase 3: MFMA 64 rows x 256 cols,
// acc[4][2]/wave, B prefetched from L2-resident Wb, clean scalar stores.
constexpr double SPd = 24.0 / 31.0;
constexpr double SP2d = SPd * SPd;
constexpr float ALPHA = (float)(-(SP2d / (SP2d + 1e-8)) * 1.4426950408889634);
constexpr float INV_SP = (float)(1.0 / SPd);

__device__ __forceinline__ void gen_cell(u32x4* Ab, int rf, int rowlo, int s, float d0) {
  float d = (d0 < 0.f) ? 1.0e9f : d0;   // sentinel -> rbf == 0
  float u = d * INV_SP;
  float C1 = (-2.0f * ALPHA) * u;
  float C0 = ALPHA * u * u;
  #pragma unroll
  for (int c8 = 0; c8 < 4; ++c8) {
    u32x4 ch;
    #pragma unroll
    for (int q = 0; q < 4; ++q) {
      const int j0 = c8 * 8 + q * 2;
      float e0 = EXP2(fmaf(C1, (float)j0,       C0) + ALPHA * (float)(j0 * j0));
      float e1 = EXP2(fmaf(C1, (float)(j0 + 1), C0) + ALPHA * (float)((j0 + 1) * (j0 + 1)));
      ch[q] = pack2(e0, e1);
    }
    Ab[rf * 1040 + s * 65 + c8 * 16 + rowlo] = ch;
  }
}

__global__ __launch_bounds__(512, 4) void fused_kernel(
    const float* __restrict__ coords, const void* __restrict__ mask,
    const u32x4* __restrict__ Wb, float* __restrict__ out)
{
  // LDS union: phase 1 = pts float4[1024] (16384B) + posof short[1024] (2048B)
  //            phase 2/3 = A tile u32x4[4][1040] (66560B)
  __shared__ __align__(16) char raw[66560];
  __shared__ float dvals[64][17];
  __shared__ int s_cnt;
  __shared__ int s_is8;

  float4* pts = (float4*)raw;
  short* posof = (short*)(raw + 16384);
  u32x4* Ab = (u32x4*)raw;

  const int tid = threadIdx.x;      // 0..511
  const int lane = tid & 63;
  const int wv = tid >> 6;          // 0..7
  const int bid = blockIdx.x;
  const int batch = bid >> 4;       // 16 blocks per batch (64 queries each)
  const int qchunk = bid & 15;

  if (tid == 0) { s_cnt = 0; s_is8 = 0; }
  __syncthreads();
  { // mask dtype detection: int32 0/1 words vs packed int8 bools
    unsigned w = ((const unsigned*)mask)[tid & 255];
    if (w > 1u) atomicOr(&s_is8, 1);
  }
  __syncthreads();
  const bool is8 = (s_is8 != 0);

  const float* cb = coords + (size_t)batch * MDIM * 3;
  const int mbase = batch * MDIM;

  // compact valid atoms into LDS: (x,y,z,|p|^2)
  #pragma unroll
  for (int r = 0; r < 2; ++r) {
    int a = r * 512 + tid;
    int v = read_mask(mask, mbase + a, is8);
    float x = cb[a*3+0], y = cb[a*3+1], z = cb[a*3+2];
    float S = fmaf(z, z, fmaf(y, y, x * x));
    unsigned long long bal = __ballot(v != 0);
    int base = 0;
    if (lane == 0) base = atomicAdd(&s_cnt, __popcll(bal));
    base = __shfl(base, 0);
    int pos = base + __popcll(bal & ((1ull << lane) - 1ull));
    if (v) {
      float4 p; p.x = x; p.y = y; p.z = z; p.w = S;
      pts[pos] = p;
    }
    posof[a] = (short)(v ? pos : -1);
  }
  __syncthreads();
  const int cnt = s_cnt;
  const int cntP = (cnt + 63) & ~63;   // pad to x64 (<= MDIM)
  for (int i = cnt + tid; i < cntP; i += 512) {
    float4 p; p.x = 0.f; p.y = 0.f; p.z = 0.f; p.w = 3.0e38f;  // d' = +huge
    pts[i] = p;
  }
  __syncthreads();

  // 8 lanes per query: lane = qi + 8*part; query-in-block qlo = wv*8 + qi
  const int qi = lane & 7;
  const int part = lane >> 3;
  const int qlo = wv * 8 + qi;
  const int qlocal = qchunk * 64 + qlo;
  const float qx = cb[qlocal*3+0], qy = cb[qlocal*3+1], qz = cb[qlocal*3+2];
  const float Q = fmaf(qz, qz, fmaf(qy, qy, qx * qx));
  const float m2x = -2.0f * qx, m2y = -2.0f * qy, m2z = -2.0f * qz;
  const int selfpos = posof[qlocal];
  const int lo = (cntP * part) >> 3;     // multiple of 8
  const int ng = cntP >> 6;              // full groups per part

  float t[16];
  #pragma unroll
  for (int i = 0; i < 16; ++i) t[i] = 3.0e38f;

  for (int g = 0; g < ng; ++g) {
    const int base = lo + g * 8;
    float s[8];
    #pragma unroll
    for (int i = 0; i < 8; ++i) {
      // rotate read order per part: parts hit 8 distinct 4-bank groups
      // (unrotated, all parts align to the same banks -> 8-way conflict)
      int idx = base + ((i + part) & 7);
      float4 p = pts[idx];
      // d' = |p|^2 - 2 q.p  (= d^2 - Q, order-preserving)
      float d = fmaf(p.z, m2z, fmaf(p.y, m2y, fmaf(p.x, m2x, p.w)));
      s[i] = (idx == selfpos) ? 3.0e38f : d;   // exclude self
    }
    // Batcher sort-8 (19 CE)
    #define CES(i,j) { float mn_ = VMIN(s[i], s[j]); float mx_ = VMAX(s[i], s[j]); s[i] = mn_; s[j] = mx_; }
    CES(0,1) CES(2,3) CES(4,5) CES(6,7)
    CES(0,2) CES(1,3) CES(4,6) CES(5,7)
    CES(1,2) CES(5,6)
    CES(0,4) CES(1,5) CES(2,6) CES(3,7)
    CES(2,4) CES(3,5)
    CES(1,2) CES(3,4) CES(5,6)
    #undef CES
    // half-clean: t[8..15] vs reversed s -> bitonic, holds 16 smallest
    #pragma unroll
    for (int i = 0; i < 8; ++i) t[8 + i] = VMIN(t[8 + i], s[7 - i]);
    // bitonic clean of 16
    #define CET(i,j) { float mn_ = VMIN(t[i], t[j]); float mx_ = VMAX(t[i], t[j]); t[i] = mn_; t[j] = mx_; }
    CET(0,8) CET(1,9) CET(2,10) CET(3,11) CET(4,12) CET(5,13) CET(6,14) CET(7,15)
    CET(0,4) CET(1,5) CET(2,6)  CET(3,7)  CET(8,12) CET(9,13) CET(10,14) CET(11,15)
    CET(0,2) CET(1,3) CET(4,6)  CET(5,7)  CET(8,10) CET(9,11) CET(12,14) CET(13,15)
    CET(0,1) CET(2,3) CET(4,5)  CET(6,7)  CET(8,9)  CET(10,11) CET(12,13) CET(14,15)
    #undef CET
  }

  // merge the 8 part-lists: bitonic merges with partners ^8, ^16, ^32
  #pragma unroll
  for (int stepi = 0; stepi < 3; ++stepi) {
    const int step = 8 << stepi;
    float o_[16], m[16];
    #pragma unroll
    for (int i = 0; i < 16; ++i) o_[i] = __shfl(t[i], lane ^ step);
    #pragma unroll
    for (int i = 0; i < 16; ++i) m[i] = VMIN(t[i], o_[15 - i]);
    #define CE(i,jj) { float a_ = VMIN(m[i], m[jj]); float b_ = VMAX(m[i], m[jj]); m[i] = a_; m[jj] = b_; }
    CE(0,8) CE(1,9) CE(2,10) CE(3,11) CE(4,12) CE(5,13) CE(6,14) CE(7,15)
    CE(0,4) CE(1,5) CE(2,6)  CE(3,7)  CE(8,12) CE(9,13) CE(10,14) CE(11,15)
    CE(0,2) CE(1,3) CE(4,6)  CE(5,7)  CE(8,10) CE(9,11) CE(12,14) CE(13,15)
    CE(0,1) CE(2,3) CE(4,5)  CE(6,7)  CE(8,9)  CE(10,11) CE(12,13) CE(14,15)
    #undef CE
    #pragma unroll
    for (int i = 0; i < 16; ++i) t[i] = m[i];
  }

  if (part == 0) {
    int mq = read_mask(mask, mbase + qlocal, is8);
    #pragma unroll
    for (int i = 0; i < 16; ++i) {
      float v = t[i];
      float d = (v > 1.0e37f) ? 24.0f : sqrtf(fmaxf(v + Q, 1e-12f)); // pad -> MAX_DIST
      dvals[qlo][i] = mq ? d : -1.0f;   // -1 sentinel => zero output row
    }
  }
  __syncthreads();   // dvals ready; pts/posof dead -> LDS reused as A tile

  // ---- phase 2: RBF A-gen (2 cells/thread; 64 rows x 16 slots) ----
  #pragma unroll
  for (int i = 0; i < 2; ++i) {
    int cellid = tid + 512 * i;          // 0..1023
    int row = cellid >> 4, slot = cellid & 15;
    gen_cell(Ab, row >> 4, row & 15, slot, dvals[row][slot]);
  }
  __syncthreads();

  // ---- phase 3: MFMA 64 rows x 256 cols; wave owns col-groups {8e+wv} ----
  f32x4 acc[4][2];
  #pragma unroll
  for (int rf = 0; rf < 4; ++rf)
    #pragma unroll
    for (int e = 0; e < 2; ++e) acc[rf][e] = (f32x4){0.f, 0.f, 0.f, 0.f};

  u32x4 bcur[2], bnxt[2];
  #pragma unroll
  for (int e = 0; e < 2; ++e)
    bcur[e] = Wb[(size_t)((e * 8 + wv) * 16) * 64 + lane];

  #pragma unroll
  for (int s = 0; s < 16; ++s) {
    if (s < 15) {
      #pragma unroll
      for (int e = 0; e < 2; ++e)
        bnxt[e] = Wb[(size_t)((e * 8 + wv) * 16 + s + 1) * 64 + lane];
    }
    s16x8 a[4], b[2];
    #pragma unroll
    for (int rf = 0; rf < 4; ++rf) {
      u32x4 ra = Ab[rf * 1040 + s * 65 + lane];
      __builtin_memcpy(&a[rf], &ra, sizeof(ra));
    }
    #pragma unroll
    for (int e = 0; e < 2; ++e) __builtin_memcpy(&b[e], &bcur[e], sizeof(u32x4));
    #pragma unroll
    for (int rf = 0; rf < 4; ++rf)
      #pragma unroll
      for (int e = 0; e < 2; ++e)
        acc[rf][e] = __builtin_amdgcn_mfma_f32_16x16x32_bf16(a[rf], b[e], acc[rf][e], 0, 0, 0);
    #pragma unroll
    for (int e = 0; e < 2; ++e) bcur[e] = bnxt[e];
  }

  // D layout: col = lane&15, row = (lane>>4)*4 + reg. Clean scalar pattern
  // (16 adjacent lanes = 64B runs) — WRITE_SIZE-exact in R1/R11/R15.
  const int qbase = mbase + qchunk * 64;
  const int rb_ = (lane >> 4) * 4;
  #pragma unroll
  for (int rf = 0; rf < 4; ++rf) {
    #pragma unroll
    for (int e = 0; e < 2; ++e) {
      const int col = (e * 8 + wv) * 16 + (lane & 15);
      #pragma unroll
      for (int r = 0; r < 4; ++r)
        out[(size_t)(qbase + rf * 16 + rb_ + r) * ODIM + col] = acc[rf][e][r];
    }
  }
}

extern "C" void kernel_launch(void* const* d_in, const int* in_sizes, int n_in,
                              void* d_out, int out_size, void* d_ws, size_t ws_size,
                              hipStream_t stream) {
  const float* coords = (const float*)d_in[0];
  const void* mask = d_in[1];
  const float* W = (const float*)d_in[2];
  float* out = (float*)d_out;
  u32x4* Wb = (u32x4*)d_ws;   // 256 KB bf16 W fragments

  hipLaunchKernelGGL(wconv_kernel, dim3(64), dim3(256), 0, stream, W, Wb);
  hipLaunchKernelGGL(fused_kernel, dim3(QTOT / 64), dim3(512), 0, stream,
                     coords, mask, Wb, out);
}

// Round 17
// 53.673 us; speedup vs baseline: 2.5445x; 1.0236x over previous
//
#include <hip/hip_runtime.h>
#include <hip/hip_bf16.h>
#include <math.h>

#define MDIM 1024
#define QTOT 65536
#define KTOP 16
#define ODIM 256
#define FDIM 512

typedef float f32x4 __attribute__((ext_vector_type(4)));
typedef short s16x8 __attribute__((ext_vector_type(8)));
typedef unsigned u32x4 __attribute__((ext_vector_type(4)));

// pinned single-instruction ops
#define VMIN(a,b)  ({float r_; asm("v_min_f32 %0,%1,%2":"=v"(r_):"v"(a),"v"(b)); r_;})
#define VMAX(a,b)  ({float r_; asm("v_max_f32 %0,%1,%2":"=v"(r_):"v"(a),"v"(b)); r_;})
#define VEXP2(x)   ({float r_; asm("v_exp_f32 %0,%1":"=v"(r_):"v"(x)); r_;})

__device__ __forceinline__ int read_mask(const void* m, int i, bool is8) {
  return is8 ? (int)((const unsigned char*)m)[i] : ((const int*)m)[i];
}

__device__ __forceinline__ unsigned pack2(float lo, float hi) {
  __hip_bfloat162 h = __float22bfloat162_rn(make_float2(lo, hi));
  unsigned u;
  __builtin_memcpy(&u, &h, sizeof(u));
  return u;
}

// sort networks on local arrays
#define CEx(A,i,j) { float mn_ = VMIN(A[i], A[j]); float mx_ = VMAX(A[i], A[j]); A[i] = mn_; A[j] = mx_; }
#define SORT8(A) \
  CEx(A,0,1) CEx(A,2,3) CEx(A,4,5) CEx(A,6,7) \
  CEx(A,0,2) CEx(A,1,3) CEx(A,4,6) CEx(A,5,7) \
  CEx(A,1,2) CEx(A,5,6) \
  CEx(A,0,4) CEx(A,1,5) CEx(A,2,6) CEx(A,3,7) \
  CEx(A,2,4) CEx(A,3,5) \
  CEx(A,1,2) CEx(A,3,4) CEx(A,5,6)
#define CLEAN8(A) \
  CEx(A,0,4) CEx(A,1,5) CEx(A,2,6) CEx(A,3,7) \
  CEx(A,0,2) CEx(A,1,3) CEx(A,4,6) CEx(A,5,7) \
  CEx(A,0,1) CEx(A,2,3) CEx(A,4,5) CEx(A,6,7)
#define CLEAN16(A) \
  CEx(A,0,8) CEx(A,1,9) CEx(A,2,10) CEx(A,3,11) CEx(A,4,12) CEx(A,5,13) CEx(A,6,14) CEx(A,7,15) \
  CEx(A,0,4) CEx(A,1,5) CEx(A,2,6)  CEx(A,3,7)  CEx(A,8,12) CEx(A,9,13) CEx(A,10,14) CEx(A,11,15) \
  CEx(A,0,2) CEx(A,1,3) CEx(A,4,6)  CEx(A,5,7)  CEx(A,8,10) CEx(A,9,11) CEx(A,12,14) CEx(A,13,15) \
  CEx(A,0,1) CEx(A,2,3) CEx(A,4,5)  CEx(A,6,7)  CEx(A,8,9)  CEx(A,10,11) CEx(A,12,13) CEx(A,14,15)

// ---------------- kernel 0: W fp32 -> bf16 fragment-layout prepass ----------
__global__ __launch_bounds__(256) void wconv_kernel(
    const float* __restrict__ W, u32x4* __restrict__ Wb)
{
  int slot = blockIdx.x * 256 + threadIdx.x;   // 0..16383
  int cg = slot >> 10;
  int rem = slot & 1023;
  int s = rem >> 6, l = rem & 63;
  int col = cg * 16 + (l & 15);
  int kk = s * 32 + (l >> 4) * 8;
  const float4* p = (const float4*)(W + (size_t)col * FDIM + kk);
  float4 a = p[0], b = p[1];
  u32x4 u0;
  u0[0] = pack2(a.x, a.y); u0[1] = pack2(a.z, a.w);
  u0[2] = pack2(b.x, b.y); u0[3] = pack2(b.z, b.w);
  Wb[(size_t)(cg * 16 + s) * 64 + l] = u0;
}

// ---------------- fused kernel: top-16 -> RBF -> projection ----------------
// grid: QTOT/64 = 1024 blocks x 512 threads (8 waves), 2 blocks/CU (71 KB LDS).
// Phase 1: per-query top-16; part p owns candidates idx = 8k+p (strided ->
//   conflict-free LDS, offset-immediate addressing). Each part keeps SORTED-8
//   (cheaper than 16); exactness guaranteed by the bound check: discarded >=
//   part's final 8th-smallest; if any part's bound < global-16th, the wave
//   reruns the exact 16-deep path (rare).
// Phase 2: RBF A-gen into union'd LDS (v_exp_f32). Phase 3: MFMA 64x256,
//   acc[4][2]/wave, B prefetched from L2-resident Wb, clean scalar stores.
constexpr double SPd = 24.0 / 31.0;
constexpr double SP2d = SPd * SPd;
constexpr float ALPHA = (float)(-(SP2d / (SP2d + 1e-8)) * 1.4426950408889634);
constexpr float INV_SP = (float)(1.0 / SPd);

__device__ __forceinline__ void gen_cell(u32x4* Ab, int rf, int rowlo, int s, float d0) {
  float d = (d0 < 0.f) ? 1.0e9f : d0;   // sentinel -> rbf == 0
  float u = d * INV_SP;
  float C1 = (-2.0f * ALPHA) * u;
  float C0 = ALPHA * u * u;
  #pragma unroll
  for (int c8 = 0; c8 < 4; ++c8) {
    u32x4 ch;
    #pragma unroll
    for (int q = 0; q < 4; ++q) {
      const int j0 = c8 * 8 + q * 2;
      float e0 = VEXP2(fmaf(C1, (float)j0,       C0) + ALPHA * (float)(j0 * j0));
      float e1 = VEXP2(fmaf(C1, (float)(j0 + 1), C0) + ALPHA * (float)((j0 + 1) * (j0 + 1)));
      ch[q] = pack2(e0, e1);
    }
    Ab[rf * 1040 + s * 65 + c8 * 16 + rowlo] = ch;
  }
}

__global__ __launch_bounds__(512, 4) void fused_kernel(
    const float* __restrict__ coords, const void* __restrict__ mask,
    const u32x4* __restrict__ Wb, float* __restrict__ out)
{
  // LDS union: phase 1 = pts float4[1024] + posof short[1024];
  //            phase 2/3 = A tile u32x4[4][1040] (66560B)
  __shared__ __align__(16) char raw[66560];
  __shared__ float dvals[64][17];
  __shared__ int s_cnt;
  __shared__ int s_is8;

  float4* pts = (float4*)raw;
  short* posof = (short*)(raw + 16384);
  u32x4* Ab = (u32x4*)raw;

  const int tid = threadIdx.x;      // 0..511
  const int lane = tid & 63;
  const int wv = tid >> 6;          // 0..7
  const int bid = blockIdx.x;
  const int batch = bid >> 4;       // 16 blocks per batch (64 queries each)
  const int qchunk = bid & 15;

  if (tid == 0) { s_cnt = 0; s_is8 = 0; }
  __syncthreads();
  { // mask dtype detection: int32 0/1 words vs packed int8 bools
    unsigned w = ((const unsigned*)mask)[tid & 255];
    if (w > 1u) atomicOr(&s_is8, 1);
  }
  __syncthreads();
  const bool is8 = (s_is8 != 0);

  const float* cb = coords + (size_t)batch * MDIM * 3;
  const int mbase = batch * MDIM;

  // compact valid atoms into LDS: (x,y,z,|p|^2)
  #pragma unroll
  for (int r = 0; r < 2; ++r) {
    int a = r * 512 + tid;
    int v = read_mask(mask, mbase + a, is8);
    float x = cb[a*3+0], y = cb[a*3+1], z = cb[a*3+2];
    float S = fmaf(z, z, fmaf(y, y, x * x));
    unsigned long long bal = __ballot(v != 0);
    int base = 0;
    if (lane == 0) base = atomicAdd(&s_cnt, __popcll(bal));
    base = __shfl(base, 0);
    int pos = base + __popcll(bal & ((1ull << lane) - 1ull));
    if (v) {
      float4 p; p.x = x; p.y = y; p.z = z; p.w = S;
      pts[pos] = p;
    }
    posof[a] = (short)(v ? pos : -1);
  }
  __syncthreads();
  const int cnt = s_cnt;
  const int cntP = (cnt + 63) & ~63;   // pad to x64 (<= MDIM)
  for (int i = cnt + tid; i < cntP; i += 512) {
    float4 p; p.x = 0.f; p.y = 0.f; p.z = 0.f; p.w = 3.0e38f;  // d' = +huge
    pts[i] = p;
  }
  __syncthreads();

  // 8 lanes per query: lane = qi + 8*part
  const int qi = lane & 7;
  const int part = lane >> 3;
  const int qlo = wv * 8 + qi;
  const int qlocal = qchunk * 64 + qlo;
  const float qx = cb[qlocal*3+0], qy = cb[qlocal*3+1], qz = cb[qlocal*3+2];
  const float Q = fmaf(qz, qz, fmaf(qy, qy, qx * qx));
  const float m2x = -2.0f * qx, m2y = -2.0f * qy, m2z = -2.0f * qz;
  const int selfpos = posof[qlocal];
  // part p owns idx = 8k + p; self matches only if (selfpos&7)==part
  const int selfk = ((selfpos & 7) == part) ? (selfpos >> 3) : -1;
  const int ngroups = cntP >> 6;
  const float4* pbase = pts + part;

  float t8[8];
  #pragma unroll
  for (int i = 0; i < 8; ++i) t8[i] = 3.0e38f;

  for (int g = 0; g < ngroups; ++g) {
    float s[8];
    #pragma unroll
    for (int i = 0; i < 8; ++i) {
      float4 p = pbase[(size_t)(g * 8 + i) * 8];   // addr: base + g*1024 + i*128
      float d = fmaf(p.z, m2z, fmaf(p.y, m2y, fmaf(p.x, m2x, p.w)));
      s[i] = (g * 8 + i == selfk) ? 3.0e38f : d;   // exclude self
    }
    SORT8(s)
    // keep 8 smallest of (t8 ∪ s): bitonic low-half + clean-8
    float m[8];
    #pragma unroll
    for (int i = 0; i < 8; ++i) m[i] = VMIN(t8[i], s[7 - i]);
    CLEAN8(m)
    #pragma unroll
    for (int i = 0; i < 8; ++i) t8[i] = m[i];
  }
  const float bound = t8[7];   // all discarded values >= bound

  // ^8: full-merge two sorted-8 -> sorted-16 (bitonic split + two clean-8)
  float t[16];
  {
    float o[8], L[8], H[8];
    #pragma unroll
    for (int i = 0; i < 8; ++i) o[i] = __shfl(t8[i], lane ^ 8);
    #pragma unroll
    for (int i = 0; i < 8; ++i) { L[i] = VMIN(t8[i], o[7 - i]); H[i] = VMAX(t8[i], o[7 - i]); }
    CLEAN8(L)
    CLEAN8(H)
    #pragma unroll
    for (int i = 0; i < 8; ++i) { t[i] = L[i]; t[8 + i] = H[i]; }
  }
  // ^16, ^32: keep 16 smallest of two sorted-16
  #pragma unroll
  for (int stepi = 0; stepi < 2; ++stepi) {
    const int step = 16 << stepi;
    float o[16], m[16];
    #pragma unroll
    for (int i = 0; i < 16; ++i) o[i] = __shfl(t[i], lane ^ step);
    #pragma unroll
    for (int i = 0; i < 16; ++i) m[i] = VMIN(t[i], o[15 - i]);
    CLEAN16(m)
    #pragma unroll
    for (int i = 0; i < 16; ++i) t[i] = m[i];
  }

  // exactness check: if any part may have discarded a true top-16 member,
  // redo this wave's queries with the exact 16-deep path (rare).
  if (__ballot(bound < t[15]) != 0ull) {
    #pragma unroll
    for (int i = 0; i < 16; ++i) t[i] = 3.0e38f;
    for (int g = 0; g < ngroups; ++g) {
      float s[8];
      #pragma unroll
      for (int i = 0; i < 8; ++i) {
        float4 p = pbase[(size_t)(g * 8 + i) * 8];
        float d = fmaf(p.z, m2z, fmaf(p.y, m2y, fmaf(p.x, m2x, p.w)));
        s[i] = (g * 8 + i == selfk) ? 3.0e38f : d;
      }
      SORT8(s)
      #pragma unroll
      for (int i = 0; i < 8; ++i) t[8 + i] = VMIN(t[8 + i], s[7 - i]);
      CLEAN16(t)
    }
    #pragma unroll
    for (int stepi = 0; stepi < 3; ++stepi) {
      const int step = 8 << stepi;
      float o[16], m[16];
      #pragma unroll
      for (int i = 0; i < 16; ++i) o[i] = __shfl(t[i], lane ^ step);
      #pragma unroll
      for (int i = 0; i < 16; ++i) m[i] = VMIN(t[i], o[15 - i]);
      CLEAN16(m)
      #pragma unroll
      for (int i = 0; i < 16; ++i) t[i] = m[i];
    }
  }

  if (part == 0) {
    int mq = read_mask(mask, mbase + qlocal, is8);
    #pragma unroll
    for (int i = 0; i < 16; ++i) {
      float v = t[i];
      float d = (v > 1.0e37f) ? 24.0f : sqrtf(fmaxf(v + Q, 1e-12f)); // pad -> MAX_DIST
      dvals[qlo][i] = mq ? d : -1.0f;   // -1 sentinel => zero output row
    }
  }
  __syncthreads();   // dvals ready; pts/posof dead -> LDS reused as A tile

  // ---- phase 2: RBF A-gen (2 cells/thread; 64 rows x 16 slots) ----
  #pragma unroll
  for (int i = 0; i < 2; ++i) {
    int cellid = tid + 512 * i;          // 0..1023
    int row = cellid >> 4, slot = cellid & 15;
    gen_cell(Ab, row >> 4, row & 15, slot, dvals[row][slot]);
  }
  __syncthreads();

  // ---- phase 3: MFMA 64 rows x 256 cols; wave owns col-groups {8e+wv} ----
  f32x4 acc[4][2];
  #pragma unroll
  for (int rf = 0; rf < 4; ++rf)
    #pragma unroll
    for (int e = 0; e < 2; ++e) acc[rf][e] = (f32x4){0.f, 0.f, 0.f, 0.f};

  u32x4 bcur[2], bnxt[2];
  #pragma unroll
  for (int e = 0; e < 2; ++e)
    bcur[e] = Wb[(size_t)((e * 8 + wv) * 16) * 64 + lane];

  #pragma unroll
  for (int s = 0; s < 16; ++s) {
    if (s < 15) {
      #pragma unroll
      for (int e = 0; e < 2; ++e)
        bnxt[e] = Wb[(size_t)((e * 8 + wv) * 16 + s + 1) * 64 + lane];
    }
    s16x8 a[4], b[2];
    #pragma unroll
    for (int rf = 0; rf < 4; ++rf) {
      u32x4 ra = Ab[rf * 1040 + s * 65 + lane];
      __builtin_memcpy(&a[rf], &ra, sizeof(ra));
    }
    #pragma unroll
    for (int e = 0; e < 2; ++e) __builtin_memcpy(&b[e], &bcur[e], sizeof(u32x4));
    #pragma unroll
    for (int rf = 0; rf < 4; ++rf)
      #pragma unroll
      for (int e = 0; e < 2; ++e)
        acc[rf][e] = __builtin_amdgcn_mfma_f32_16x16x32_bf16(a[rf], b[e], acc[rf][e], 0, 0, 0);
    #pragma unroll
    for (int e = 0; e < 2; ++e) bcur[e] = bnxt[e];
  }

  // D layout: col = lane&15, row = (lane>>4)*4 + reg. Clean scalar pattern
  // (16 adjacent lanes = 64B runs) — WRITE_SIZE-exact in R1/R11/R15.
  const int qbase = mbase + qchunk * 64;
  const int rb_ = (lane >> 4) * 4;
  #pragma unroll
  for (int rf = 0; rf < 4; ++rf) {
    #pragma unroll
    for (int e = 0; e < 2; ++e) {
      const int col = (e * 8 + wv) * 16 + (lane & 15);
      #pragma unroll
      for (int r = 0; r < 4; ++r)
        out[(size_t)(qbase + rf * 16 + rb_ + r) * ODIM + col] = acc[rf][e][r];
    }
  }
}

extern "C" void kernel_launch(void* const* d_in, const int* in_sizes, int n_in,
                              void* d_out, int out_size, void* d_ws, size_t ws_size,
                              hipStream_t stream) {
  const float* coords = (const float*)d_in[0];
  const void* mask = d_in[1];
  const float* W = (const float*)d_in[2];
  float* out = (float*)d_out;
  u32x4* Wb = (u32x4*)d_ws;   // 256 KB bf16 W fragments

  hipLaunchKernelGGL(wconv_kernel, dim3(64), dim3(256), 0, stream, W, Wb);
  hipLaunchKernelGGL(fused_kernel, dim3(QTOT / 64), dim3(512), 0, stream,
                     coords, mask, Wb, out);
}